// Round 5
// baseline (351.929 us; speedup 1.0000x reference)
//
#include <hip/hip_runtime.h>

#define N_NODES 50000
#define N_REL   3
#define N_EDGE  200000
#define RN      (N_REL * N_NODES)      // 150000 (relation, node) pairs for norms
#define RE      (N_REL * N_EDGE)       // 600000 edges total
// dims: DIN=128, DHID=128, DOUT=64 (GEMM K is always 128)

typedef short bf16x8 __attribute__((ext_vector_type(8)));
typedef float f32x4  __attribute__((ext_vector_type(4)));

// ---------------- degree count ----------------
__global__ __launch_bounds__(256) void deg_count_kernel(
    const int* __restrict__ src, const int* __restrict__ dst,
    float* __restrict__ odeg, float* __restrict__ ideg)
{
    int i = blockIdx.x * 256 + threadIdx.x;
    if (i >= RE) return;
    int r = i / N_EDGE;
    unsafeAtomicAdd(&odeg[r * N_NODES + src[i]], 1.0f);
    unsafeAtomicAdd(&ideg[r * N_NODES + dst[i]], 1.0f);
}

__global__ __launch_bounds__(256) void norm_kernel(
    float* __restrict__ odeg, float* __restrict__ ideg)
{
    int i = blockIdx.x * 256 + threadIdx.x;
    if (i >= RN) return;
    odeg[i] = rsqrtf(fmaxf(odeg[i], 1.0f));
    ideg[i] = rsqrtf(fmaxf(ideg[i], 1.0f));
}

// ---------------- exclusive scan over N_NODES combined in-degree (sum of 3 rels) ----------------
__global__ __launch_bounds__(256) void scan1_kernel(
    const float* __restrict__ ideg, int* __restrict__ off, int* __restrict__ bsums)
{
    __shared__ int tsum[256];
    int tid  = threadIdx.x;
    int base = blockIdx.x * 1024 + tid * 4;
    int c[4], s = 0;
    #pragma unroll
    for (int j = 0; j < 4; ++j) {
        int idx = base + j;
        c[j] = (idx < N_NODES)
             ? (int)(ideg[idx] + ideg[N_NODES + idx] + ideg[2 * N_NODES + idx]) : 0;
        s += c[j];
    }
    tsum[tid] = s;
    __syncthreads();
    #pragma unroll
    for (int d = 1; d < 256; d <<= 1) {
        int v   = tsum[tid];
        int add = (tid >= d) ? tsum[tid - d] : 0;
        __syncthreads();
        tsum[tid] = v + add;
        __syncthreads();
    }
    int run = tsum[tid] - s;
    #pragma unroll
    for (int j = 0; j < 4; ++j) {
        if (base + j < N_NODES) off[base + j] = run;
        run += c[j];
    }
    if (tid == 255) bsums[blockIdx.x] = tsum[255];
}

__global__ __launch_bounds__(256) void scan2_kernel(int* __restrict__ bsums, int nb)
{
    __shared__ int t[256];
    int tid = threadIdx.x;
    int v0  = (tid < nb) ? bsums[tid] : 0;
    t[tid] = v0;
    __syncthreads();
    #pragma unroll
    for (int d = 1; d < 256; d <<= 1) {
        int v   = t[tid];
        int add = (tid >= d) ? t[tid - d] : 0;
        __syncthreads();
        t[tid] = v + add;
        __syncthreads();
    }
    if (tid < nb) bsums[tid] = t[tid] - v0;
}

__global__ __launch_bounds__(256) void scan3_kernel(
    int* __restrict__ off, int* __restrict__ cursor, const int* __restrict__ bsums)
{
    int tid  = threadIdx.x;
    int base = blockIdx.x * 1024 + tid * 4;
    int add  = bsums[blockIdx.x];
    #pragma unroll
    for (int j = 0; j < 4; ++j) {
        if (base + j < N_NODES) {
            int v = off[base + j] + add;
            off[base + j]    = v;
            cursor[base + j] = v;
        }
    }
    if (blockIdx.x == 0 && tid == 0) off[N_NODES] = RE;
}

// ---------------- CSR fill: bin by dst; payload = (r*N+src, onorm[r][src]*inorm[r][dst]) ----------------
__global__ __launch_bounds__(256) void fill_kernel(
    const int* __restrict__ src, const int* __restrict__ dst,
    const float* __restrict__ onorm, const float* __restrict__ inorm,
    int* __restrict__ cursor, int2* __restrict__ csr)
{
    int i = blockIdx.x * 256 + threadIdx.x;
    if (i >= N_EDGE) return;
    int r = blockIdx.y;
    int s = src[r * N_EDGE + i];
    int t = dst[r * N_EDGE + i];
    float wv = onorm[r * N_NODES + s] * inorm[r * N_NODES + t];
    int pos = atomicAdd(&cursor[t], 1);
    csr[pos] = make_int2(r * N_NODES + s, __float_as_int(wv));
}

// ---------------- f32 -> bf16 (RNE) ----------------
__device__ __forceinline__ unsigned short f2bf(float f) {
    unsigned u = __float_as_uint(f);
    u = (u + 0x7fffu + ((u >> 16) & 1u)) >> 16;
    return (unsigned short)u;
}
__device__ __forceinline__ unsigned pack_bf2(float lo, float hi) {
    return (unsigned)f2bf(lo) | ((unsigned)f2bf(hi) << 16);
}

// ---------------- W transpose+convert: Wt[rel][n][k] = bf16(W[rel][k][n]) ----------------
__global__ __launch_bounds__(256) void wtrans_kernel(
    const float* __restrict__ W, unsigned short* __restrict__ Wt,
    int ncols, int total)
{
    int i = blockIdx.x * 256 + threadIdx.x;
    if (i >= total) return;
    int rel = i / (128 * ncols);
    int rem = i - rel * 128 * ncols;
    int k   = rem / ncols;
    int n   = rem - k * ncols;
    Wt[((size_t)(rel * ncols + n)) * 128 + k] = f2bf(W[i]);
}

// ---------------- MFMA GEMM: Y[rel][row][0:NCOLS] = A[row,0:128] @ W[rel] ----------------
// 64-row strip / block, 4 waves. Column space (3*NCOLS) split across waves:
// each wave holds a-frags for ALL 64 rows (16x bf16x8) and walks CTW 16-col
// tiles; 4 B-frag loads serve 16 MFMAs (reuse 4x), next tile's B prefetched.
// D layout: col=lane&15, row=(lane>>4)*4+reg (m89-verified).
template <bool ABF16, int NCOLS>
__global__ __launch_bounds__(256, 4) void gemm_mfma(
    const void* __restrict__ Av, const unsigned short* __restrict__ Wt,
    unsigned short* __restrict__ Y, int nrows)
{
    __shared__ unsigned As[64 * 68];   // word = 2 bf16; row stride 68 words

    const int tid = threadIdx.x;
    const int mt  = blockIdx.x * 64;

    if constexpr (ABF16) {
        const uint4* Ab = (const uint4*)Av;     // bf16 rows of 128 = 16 uint4
        #pragma unroll
        for (int p = 0; p < 4; ++p) {
            int q   = p * 256 + tid;            // 1024 uint4 total
            int row = q >> 4, w4 = q & 15;
            int gr  = mt + row;
            uint4 v = make_uint4(0u, 0u, 0u, 0u);
            if (gr < nrows) v = Ab[(size_t)gr * 16 + w4];
            As[row * 68 + w4 * 4 + 0] = v.x;
            As[row * 68 + w4 * 4 + 1] = v.y;
            As[row * 68 + w4 * 4 + 2] = v.z;
            As[row * 68 + w4 * 4 + 3] = v.w;
        }
    } else {
        const float* A = (const float*)Av;
        #pragma unroll
        for (int p = 0; p < 16; ++p) {
            int q   = tid + p * 256;
            int row = q >> 6, wc = q & 63;
            int gr  = mt + row;
            float2 v = make_float2(0.f, 0.f);
            if (gr < nrows) v = *reinterpret_cast<const float2*>(&A[(size_t)gr * 128 + wc * 2]);
            As[row * 68 + wc] = pack_bf2(v.x, v.y);
        }
    }
    __syncthreads();

    const int w  = tid >> 6;
    const int l  = tid & 63;
    const int g  = l >> 4;
    const int lr = l & 15;

    // a-frags for all 64 rows (row-frag m covers rows m*16..m*16+15)
    bf16x8 a[4][4];
    #pragma unroll
    for (int m = 0; m < 4; ++m)
        #pragma unroll
        for (int kb = 0; kb < 4; ++kb)
            a[m][kb] = *reinterpret_cast<const bf16x8*>(&As[(m * 16 + lr) * 68 + kb * 16 + g * 4]);

    constexpr int TPR = NCOLS / 16;       // 16-col tiles per relation
    constexpr int CTW = (3 * TPR) / 4;    // tiles per wave: 6 (L1) / 3 (L2)
    const int ct0 = w * CTW;

    auto bptr = [&](int ct) {
        int rel = ct / TPR, c16 = ct % TPR;
        return &Wt[((size_t)(rel * NCOLS + c16 * 16 + lr)) * 128 + g * 8];
    };

    bf16x8 bc[4];
    {
        const unsigned short* wp = bptr(ct0);
        #pragma unroll
        for (int kb = 0; kb < 4; ++kb)
            bc[kb] = *reinterpret_cast<const bf16x8*>(wp + kb * 32);
    }

    #pragma unroll 1
    for (int t = 0; t < CTW; ++t) {
        int ct = ct0 + t;
        bf16x8 bn[4];
        if (t + 1 < CTW) {
            const unsigned short* wp = bptr(ct + 1);
            #pragma unroll
            for (int kb = 0; kb < 4; ++kb)
                bn[kb] = *reinterpret_cast<const bf16x8*>(wp + kb * 32);
        }

        f32x4 acc[4];
        #pragma unroll
        for (int m = 0; m < 4; ++m) acc[m] = (f32x4){0.f, 0.f, 0.f, 0.f};
        #pragma unroll
        for (int kb = 0; kb < 4; ++kb)
            #pragma unroll
            for (int m = 0; m < 4; ++m)
                acc[m] = __builtin_amdgcn_mfma_f32_16x16x32_bf16(a[m][kb], bc[kb], acc[m], 0, 0, 0);

        int rel = ct / TPR, c16 = ct % TPR;
        #pragma unroll
        for (int m = 0; m < 4; ++m)
            #pragma unroll
            for (int i = 0; i < 4; ++i) {
                int grow = mt + m * 16 + g * 4 + i;
                if (grow < nrows)
                    Y[((size_t)rel * N_NODES + grow) * NCOLS + c16 * 16 + lr] = f2bf(acc[m][i]);
            }

        if (t + 1 < CTW) {
            #pragma unroll
            for (int kb = 0; kb < 4; ++kb) bc[kb] = bn[kb];
        }
    }
}

// ---------------- gather aggregation, layer 1 (D=128), fused CSR, unroll-8 ----------------
// One wave per dst node; lane holds 2 dims. Epilogue: bias + ReLU, write h as bf16.
__global__ __launch_bounds__(256) void agg128_kernel(
    const unsigned* __restrict__ Y, const int2* __restrict__ csr,
    const int* __restrict__ off, const float* __restrict__ b, unsigned* __restrict__ hbf)
{
    int wid  = (blockIdx.x * 256 + threadIdx.x) >> 6;
    int lane = threadIdx.x & 63;
    if (wid >= N_NODES) return;

    int e = off[wid], end = off[wid + 1];
    float a0 = 0.f, a1 = 0.f;

    for (; e + 8 <= end; e += 8) {
        int2 p[8]; unsigned y[8];
        #pragma unroll
        for (int j = 0; j < 8; ++j) p[j] = csr[e + j];
        #pragma unroll
        for (int j = 0; j < 8; ++j) y[j] = Y[(size_t)p[j].x * 64 + lane];
        #pragma unroll
        for (int j = 0; j < 8; ++j) {
            float wv = __int_as_float(p[j].y);
            a0 = fmaf(wv, __uint_as_float(y[j] << 16), a0);
            a1 = fmaf(wv, __uint_as_float(y[j] & 0xffff0000u), a1);
        }
    }
    if (e + 4 <= end) {
        int2 p[4]; unsigned y[4];
        #pragma unroll
        for (int j = 0; j < 4; ++j) p[j] = csr[e + j];
        #pragma unroll
        for (int j = 0; j < 4; ++j) y[j] = Y[(size_t)p[j].x * 64 + lane];
        #pragma unroll
        for (int j = 0; j < 4; ++j) {
            float wv = __int_as_float(p[j].y);
            a0 = fmaf(wv, __uint_as_float(y[j] << 16), a0);
            a1 = fmaf(wv, __uint_as_float(y[j] & 0xffff0000u), a1);
        }
        e += 4;
    }
    for (; e < end; ++e) {
        int2 p = csr[e];
        float wv = __int_as_float(p.y);
        unsigned y = Y[(size_t)p.x * 64 + lane];
        a0 = fmaf(wv, __uint_as_float(y << 16), a0);
        a1 = fmaf(wv, __uint_as_float(y & 0xffff0000u), a1);
    }

    int d = lane * 2;
    float o0 = a0 + b[d]     + b[128 + d]     + b[256 + d];
    float o1 = a1 + b[d + 1] + b[128 + d + 1] + b[256 + d + 1];
    hbf[(size_t)wid * 64 + lane] = pack_bf2(fmaxf(o0, 0.f), fmaxf(o1, 0.f));
}

// ---------------- gather aggregation, layer 2 (D=64), fused CSR, unroll-8 ----------------
__global__ __launch_bounds__(256) void agg64_kernel(
    const unsigned short* __restrict__ Y, const int2* __restrict__ csr,
    const int* __restrict__ off, const float* __restrict__ b, float* __restrict__ out)
{
    int wid  = (blockIdx.x * 256 + threadIdx.x) >> 6;
    int lane = threadIdx.x & 63;
    if (wid >= N_NODES) return;

    int e = off[wid], end = off[wid + 1];
    float a = 0.f;

    for (; e + 8 <= end; e += 8) {
        int2 p[8]; unsigned short y[8];
        #pragma unroll
        for (int j = 0; j < 8; ++j) p[j] = csr[e + j];
        #pragma unroll
        for (int j = 0; j < 8; ++j) y[j] = Y[(size_t)p[j].x * 64 + lane];
        #pragma unroll
        for (int j = 0; j < 8; ++j)
            a = fmaf(__int_as_float(p[j].y),
                     __uint_as_float(((unsigned)y[j]) << 16), a);
    }
    if (e + 4 <= end) {
        int2 p[4]; unsigned short y[4];
        #pragma unroll
        for (int j = 0; j < 4; ++j) p[j] = csr[e + j];
        #pragma unroll
        for (int j = 0; j < 4; ++j) y[j] = Y[(size_t)p[j].x * 64 + lane];
        #pragma unroll
        for (int j = 0; j < 4; ++j)
            a = fmaf(__int_as_float(p[j].y),
                     __uint_as_float(((unsigned)y[j]) << 16), a);
        e += 4;
    }
    for (; e < end; ++e) {
        int2 p = csr[e];
        a = fmaf(__int_as_float(p.y),
                 __uint_as_float(((unsigned)Y[(size_t)p.x * 64 + lane]) << 16), a);
    }

    float bs = b[lane] + b[64 + lane] + b[128 + lane];
    out[(size_t)wid * 64 + lane] = a + bs;
}

extern "C" void kernel_launch(void* const* d_in, const int* in_sizes, int n_in,
                              void* d_out, int out_size, void* d_ws, size_t ws_size,
                              hipStream_t stream)
{
    const float* x   = (const float*)d_in[0];   // [N,128]
    const float* W1  = (const float*)d_in[1];   // [3,128,128]
    const float* b1  = (const float*)d_in[2];   // [3,128]
    const float* W2  = (const float*)d_in[3];   // [3,128,64]
    const float* b2  = (const float*)d_in[4];   // [3,64]
    const int*   src = (const int*)d_in[5];     // [3,E]
    const int*   dst = (const int*)d_in[6];     // [3,E]
    float*       out = (float*)d_out;           // [N,64]

    // workspace layout
    char* w = (char*)d_ws;
    float* onorm  = (float*)w;                 w += (size_t)RN * 4;
    float* inorm  = (float*)w;                 w += (size_t)RN * 4;
    int*   off    = (int*)w;                   w += (size_t)(N_NODES + 1) * 4;
    int*   cursor = (int*)w;                   w += (size_t)N_NODES * 4;
    int*   bsums  = (int*)w;                   w += 1024;
    w = (char*)(((uintptr_t)w + 255) & ~(uintptr_t)255);
    int2*  csr    = (int2*)w;                  w += (size_t)RE * 8;
    unsigned* hbf = (unsigned*)w;              w += (size_t)N_NODES * 64 * 4;   // bf16 h [N,128]
    unsigned short* Ybf = (unsigned short*)w;  w += (size_t)N_REL * N_NODES * 128 * 2;
    unsigned short* Wt1 = (unsigned short*)w;  w += (size_t)N_REL * 128 * 128 * 2;
    unsigned short* Wt2 = (unsigned short*)w;  // 3*64*128*2

    const int SCAN_BLOCKS = (N_NODES + 1023) / 1024;   // 49
    const int mtiles = (N_NODES + 63) / 64;            // 782

    // 0) weight transpose+convert (tiny)
    wtrans_kernel<<<(3 * 128 * 128 + 255) / 256, 256, 0, stream>>>(W1, Wt1, 128, 3 * 128 * 128);
    wtrans_kernel<<<(3 * 128 * 64 + 255) / 256, 256, 0, stream>>>(W2, Wt2, 64, 3 * 128 * 64);

    // 1) degrees
    hipMemsetAsync(onorm, 0, (size_t)2 * RN * 4, stream);
    deg_count_kernel<<<(RE + 255) / 256, 256, 0, stream>>>(src, dst, onorm, inorm);

    // 2) CSR offsets from combined in-degree (before norm overwrites counts)
    scan1_kernel<<<SCAN_BLOCKS, 256, 0, stream>>>(inorm, off, bsums);
    scan2_kernel<<<1, 256, 0, stream>>>(bsums, SCAN_BLOCKS);
    scan3_kernel<<<SCAN_BLOCKS, 256, 0, stream>>>(off, cursor, bsums);

    // 3) norms, then CSR fill (weight folds inorm*onorm; index folds relation)
    norm_kernel<<<(RN + 255) / 256, 256, 0, stream>>>(onorm, inorm);
    fill_kernel<<<dim3((N_EDGE + 255) / 256, N_REL), 256, 0, stream>>>(
        src, dst, onorm, inorm, cursor, csr);

    // 4) layer 1: Y_r = x @ W1_r (bf16, MFMA), gather-aggregate + bias + ReLU -> hbf (bf16)
    gemm_mfma<false, 128><<<mtiles, 256, 0, stream>>>(x, Wt1, Ybf, N_NODES);
    agg128_kernel<<<(N_NODES + 3) / 4, 256, 0, stream>>>((const unsigned*)Ybf, csr, off, b1, hbf);

    // 5) layer 2: Y_r = hbf @ W2_r (bf16, MFMA), gather-aggregate into out
    gemm_mfma<true, 64><<<mtiles, 256, 0, stream>>>(hbf, Wt2, Ybf, N_NODES);
    agg64_kernel<<<(N_NODES + 3) / 4, 256, 0, stream>>>(Ybf, csr, off, b2, out);
}

// Round 6
// 306.661 us; speedup vs baseline: 1.1476x; 1.1476x over previous
//
#include <hip/hip_runtime.h>

#define N_NODES 50000
#define N_REL   3
#define N_EDGE  200000
#define RN      (N_REL * N_NODES)      // 150000 (relation, node) pairs for norms
#define RE      (N_REL * N_EDGE)       // 600000 edges total
// dims: DIN=128, DHID=128, DOUT=64 (GEMM K is always 128)

typedef short bf16x8 __attribute__((ext_vector_type(8)));
typedef float f32x4  __attribute__((ext_vector_type(4)));

// ---------------- degree count ----------------
__global__ __launch_bounds__(256) void deg_count_kernel(
    const int* __restrict__ src, const int* __restrict__ dst,
    float* __restrict__ odeg, float* __restrict__ ideg)
{
    int i = blockIdx.x * 256 + threadIdx.x;
    if (i >= RE) return;
    int r = i / N_EDGE;
    unsafeAtomicAdd(&odeg[r * N_NODES + src[i]], 1.0f);
    unsafeAtomicAdd(&ideg[r * N_NODES + dst[i]], 1.0f);
}

__global__ __launch_bounds__(256) void norm_kernel(
    float* __restrict__ odeg, float* __restrict__ ideg)
{
    int i = blockIdx.x * 256 + threadIdx.x;
    if (i >= RN) return;
    odeg[i] = rsqrtf(fmaxf(odeg[i], 1.0f));
    ideg[i] = rsqrtf(fmaxf(ideg[i], 1.0f));
}

// ---------------- exclusive scan over N_NODES combined in-degree (sum of 3 rels) ----------------
__global__ __launch_bounds__(256) void scan1_kernel(
    const float* __restrict__ ideg, int* __restrict__ off, int* __restrict__ bsums)
{
    __shared__ int tsum[256];
    int tid  = threadIdx.x;
    int base = blockIdx.x * 1024 + tid * 4;
    int c[4], s = 0;
    #pragma unroll
    for (int j = 0; j < 4; ++j) {
        int idx = base + j;
        c[j] = (idx < N_NODES)
             ? (int)(ideg[idx] + ideg[N_NODES + idx] + ideg[2 * N_NODES + idx]) : 0;
        s += c[j];
    }
    tsum[tid] = s;
    __syncthreads();
    #pragma unroll
    for (int d = 1; d < 256; d <<= 1) {
        int v   = tsum[tid];
        int add = (tid >= d) ? tsum[tid - d] : 0;
        __syncthreads();
        tsum[tid] = v + add;
        __syncthreads();
    }
    int run = tsum[tid] - s;
    #pragma unroll
    for (int j = 0; j < 4; ++j) {
        if (base + j < N_NODES) off[base + j] = run;
        run += c[j];
    }
    if (tid == 255) bsums[blockIdx.x] = tsum[255];
}

__global__ __launch_bounds__(256) void scan2_kernel(int* __restrict__ bsums, int nb)
{
    __shared__ int t[256];
    int tid = threadIdx.x;
    int v0  = (tid < nb) ? bsums[tid] : 0;
    t[tid] = v0;
    __syncthreads();
    #pragma unroll
    for (int d = 1; d < 256; d <<= 1) {
        int v   = t[tid];
        int add = (tid >= d) ? t[tid - d] : 0;
        __syncthreads();
        t[tid] = v + add;
        __syncthreads();
    }
    if (tid < nb) bsums[tid] = t[tid] - v0;
}

__global__ __launch_bounds__(256) void scan3_kernel(
    int* __restrict__ off, int* __restrict__ cursor, const int* __restrict__ bsums)
{
    int tid  = threadIdx.x;
    int base = blockIdx.x * 1024 + tid * 4;
    int add  = bsums[blockIdx.x];
    #pragma unroll
    for (int j = 0; j < 4; ++j) {
        if (base + j < N_NODES) {
            int v = off[base + j] + add;
            off[base + j]    = v;
            cursor[base + j] = v;
        }
    }
    if (blockIdx.x == 0 && tid == 0) off[N_NODES] = RE;
}

// ---------------- CSR fill: bin by dst; payload = (r*N+src, onorm[r][src]*inorm[r][dst]) ----------------
__global__ __launch_bounds__(256) void fill_kernel(
    const int* __restrict__ src, const int* __restrict__ dst,
    const float* __restrict__ onorm, const float* __restrict__ inorm,
    int* __restrict__ cursor, int2* __restrict__ csr)
{
    int i = blockIdx.x * 256 + threadIdx.x;
    if (i >= N_EDGE) return;
    int r = blockIdx.y;
    int s = src[r * N_EDGE + i];
    int t = dst[r * N_EDGE + i];
    float wv = onorm[r * N_NODES + s] * inorm[r * N_NODES + t];
    int pos = atomicAdd(&cursor[t], 1);
    csr[pos] = make_int2(r * N_NODES + s, __float_as_int(wv));
}

// ---------------- f32 -> bf16 (RNE) ----------------
__device__ __forceinline__ unsigned short f2bf(float f) {
    unsigned u = __float_as_uint(f);
    u = (u + 0x7fffu + ((u >> 16) & 1u)) >> 16;
    return (unsigned short)u;
}
__device__ __forceinline__ unsigned pack_bf2(float lo, float hi) {
    return (unsigned)f2bf(lo) | ((unsigned)f2bf(hi) << 16);
}

// ---------------- W -> fragment-linear bf16 layout ----------------
// B element (rel, k, n):  frag f = (rel*(ncols/16) + n/16)*4 + k/32
// ushort idx = f*512 + ((k&31)/8)*128 + (n&15)*8 + (k&7)
// so a wave's b-frag read (lane = g*16+lr, 16B) is 1KB contiguous per frag.
__global__ __launch_bounds__(256) void wtrans_kernel(
    const float* __restrict__ W, unsigned short* __restrict__ Wtf,
    int ncols, int total)
{
    int i = blockIdx.x * 256 + threadIdx.x;
    if (i >= total) return;
    int rel = i / (128 * ncols);
    int rem = i - rel * 128 * ncols;
    int k   = rem / ncols;
    int n   = rem - k * ncols;
    int f   = (rel * (ncols / 16) + (n >> 4)) * 4 + (k >> 5);
    int idx = f * 512 + ((k & 31) >> 3) * 128 + (n & 15) * 8 + (k & 7);
    Wtf[idx] = f2bf(W[i]);
}

// ---------------- MFMA GEMM: Y[rel][row][0:NCOLS] = A[row,0:128] @ W[rel] ----------------
// 64-row strip / block, 4 waves; wave w owns rows w*16..w*16+15 and walks ALL
// column groups (64 cols each). B staged per-group in LDS (fragment-linear,
// double-buffered, issue-early/write-late). Stores grouped so each row's 128B
// line is covered by 4 adjacent stores (write-clean, round-4-verified).
// D layout: col=lane&15, row=(lane>>4)*4+reg (m89-verified).
template <bool ABF16, int NCOLS>
__global__ __launch_bounds__(256) void gemm_mfma(
    const void* __restrict__ Av, const unsigned short* __restrict__ Wtf,
    unsigned short* __restrict__ Y, int nrows)
{
    __shared__ unsigned As[64 * 68];     // A tile, word = 2 bf16, row stride 68 words
    __shared__ unsigned Ws[2][4096];     // 2 x 16KB: one 64-col group of B frags

    const int tid = threadIdx.x;
    const int mt  = blockIdx.x * 64;
    const uint4* Wt4 = (const uint4*)Wtf;

    // ---- stage A ----
    if constexpr (ABF16) {
        const uint4* Ab = (const uint4*)Av;     // bf16 rows of 128 = 16 uint4
        #pragma unroll
        for (int p = 0; p < 4; ++p) {
            int q   = p * 256 + tid;
            int row = q >> 4, w4 = q & 15;
            int gr  = mt + row;
            uint4 v = make_uint4(0u, 0u, 0u, 0u);
            if (gr < nrows) v = Ab[(size_t)gr * 16 + w4];
            As[row * 68 + w4 * 4 + 0] = v.x;
            As[row * 68 + w4 * 4 + 1] = v.y;
            As[row * 68 + w4 * 4 + 2] = v.z;
            As[row * 68 + w4 * 4 + 3] = v.w;
        }
    } else {
        const float* A = (const float*)Av;
        #pragma unroll
        for (int p = 0; p < 16; ++p) {
            int q   = tid + p * 256;
            int row = q >> 6, wc = q & 63;
            int gr  = mt + row;
            float2 v = make_float2(0.f, 0.f);
            if (gr < nrows) v = *reinterpret_cast<const float2*>(&A[(size_t)gr * 128 + wc * 2]);
            As[row * 68 + wc] = pack_bf2(v.x, v.y);
        }
    }

    // ---- stage W group 0 ----
    #pragma unroll
    for (int p = 0; p < 4; ++p) {
        uint4 v = Wt4[tid + p * 256];
        *reinterpret_cast<uint4*>(&Ws[0][(tid + p * 256) * 4]) = v;
    }
    __syncthreads();

    const int w  = tid >> 6;
    const int l  = tid & 63;
    const int g  = l >> 4;
    const int lr = l & 15;
    const int ar = w * 16 + lr;

    bf16x8 a[4];
    #pragma unroll
    for (int kb = 0; kb < 4; ++kb)
        a[kb] = *reinterpret_cast<const bf16x8*>(&As[ar * 68 + kb * 16 + g * 4]);

    constexpr int TPR  = NCOLS / 16;     // 16-col tiles per relation
    constexpr int NGRP = 3 * NCOLS / 64; // 64-col groups total (6 or 3)
    const int boff = (g * 16 + lr) * 4;  // lane's word offset within a frag

    int cur = 0;
    #pragma unroll 1
    for (int grp = 0; grp < NGRP; ++grp) {
        // issue next group's global loads early (latency hides under MFMA)
        uint4 st[4];
        if (grp + 1 < NGRP) {
            #pragma unroll
            for (int p = 0; p < 4; ++p)
                st[p] = Wt4[(grp + 1) * 1024 + tid + p * 256];
        }

        // compute this group: 4 x 16-col tiles
        f32x4 acc[4];
        #pragma unroll
        for (int ct4 = 0; ct4 < 4; ++ct4) {
            acc[ct4] = (f32x4){0.f, 0.f, 0.f, 0.f};
            #pragma unroll
            for (int kb = 0; kb < 4; ++kb) {
                bf16x8 b = *reinterpret_cast<const bf16x8*>(
                    &Ws[cur][(ct4 * 4 + kb) * 256 + boff]);
                acc[ct4] = __builtin_amdgcn_mfma_f32_16x16x32_bf16(a[kb], b, acc[ct4], 0, 0, 0);
            }
        }

        // stores: per output row, 4 adjacent 32B stores cover the 128B line
        int gct0 = grp * 4;
        int rel  = gct0 / TPR;
        int cb   = (gct0 % TPR) * 16;
        #pragma unroll
        for (int i = 0; i < 4; ++i) {
            int grow = mt + w * 16 + g * 4 + i;
            if (grow < nrows) {
                size_t rowbase = ((size_t)rel * N_NODES + grow) * NCOLS + cb;
                #pragma unroll
                for (int ct4 = 0; ct4 < 4; ++ct4)
                    Y[rowbase + ct4 * 16 + lr] = f2bf(acc[ct4][i]);
            }
        }

        // write-late: commit the prefetched group to the other buffer
        if (grp + 1 < NGRP) {
            #pragma unroll
            for (int p = 0; p < 4; ++p)
                *reinterpret_cast<uint4*>(&Ws[cur ^ 1][(tid + p * 256) * 4]) = st[p];
        }
        __syncthreads();
        cur ^= 1;
    }
}

// ---------------- gather aggregation, layer 1 (D=128), fused CSR, unroll-8 ----------------
// One wave per dst node; lane holds 2 dims. Epilogue: bias + ReLU, write h as bf16.
__global__ __launch_bounds__(256) void agg128_kernel(
    const unsigned* __restrict__ Y, const int2* __restrict__ csr,
    const int* __restrict__ off, const float* __restrict__ b, unsigned* __restrict__ hbf)
{
    int wid  = (blockIdx.x * 256 + threadIdx.x) >> 6;
    int lane = threadIdx.x & 63;
    if (wid >= N_NODES) return;

    int e = off[wid], end = off[wid + 1];
    float a0 = 0.f, a1 = 0.f;

    for (; e + 8 <= end; e += 8) {
        int2 p[8]; unsigned y[8];
        #pragma unroll
        for (int j = 0; j < 8; ++j) p[j] = csr[e + j];
        #pragma unroll
        for (int j = 0; j < 8; ++j) y[j] = Y[(size_t)p[j].x * 64 + lane];
        #pragma unroll
        for (int j = 0; j < 8; ++j) {
            float wv = __int_as_float(p[j].y);
            a0 = fmaf(wv, __uint_as_float(y[j] << 16), a0);
            a1 = fmaf(wv, __uint_as_float(y[j] & 0xffff0000u), a1);
        }
    }
    if (e + 4 <= end) {
        int2 p[4]; unsigned y[4];
        #pragma unroll
        for (int j = 0; j < 4; ++j) p[j] = csr[e + j];
        #pragma unroll
        for (int j = 0; j < 4; ++j) y[j] = Y[(size_t)p[j].x * 64 + lane];
        #pragma unroll
        for (int j = 0; j < 4; ++j) {
            float wv = __int_as_float(p[j].y);
            a0 = fmaf(wv, __uint_as_float(y[j] << 16), a0);
            a1 = fmaf(wv, __uint_as_float(y[j] & 0xffff0000u), a1);
        }
        e += 4;
    }
    for (; e < end; ++e) {
        int2 p = csr[e];
        float wv = __int_as_float(p.y);
        unsigned y = Y[(size_t)p.x * 64 + lane];
        a0 = fmaf(wv, __uint_as_float(y << 16), a0);
        a1 = fmaf(wv, __uint_as_float(y & 0xffff0000u), a1);
    }

    int d = lane * 2;
    float o0 = a0 + b[d]     + b[128 + d]     + b[256 + d];
    float o1 = a1 + b[d + 1] + b[128 + d + 1] + b[256 + d + 1];
    hbf[(size_t)wid * 64 + lane] = pack_bf2(fmaxf(o0, 0.f), fmaxf(o1, 0.f));
}

// ---------------- gather aggregation, layer 2 (D=64), fused CSR, unroll-8 ----------------
__global__ __launch_bounds__(256) void agg64_kernel(
    const unsigned short* __restrict__ Y, const int2* __restrict__ csr,
    const int* __restrict__ off, const float* __restrict__ b, float* __restrict__ out)
{
    int wid  = (blockIdx.x * 256 + threadIdx.x) >> 6;
    int lane = threadIdx.x & 63;
    if (wid >= N_NODES) return;

    int e = off[wid], end = off[wid + 1];
    float a = 0.f;

    for (; e + 8 <= end; e += 8) {
        int2 p[8]; unsigned short y[8];
        #pragma unroll
        for (int j = 0; j < 8; ++j) p[j] = csr[e + j];
        #pragma unroll
        for (int j = 0; j < 8; ++j) y[j] = Y[(size_t)p[j].x * 64 + lane];
        #pragma unroll
        for (int j = 0; j < 8; ++j)
            a = fmaf(__int_as_float(p[j].y),
                     __uint_as_float(((unsigned)y[j]) << 16), a);
    }
    if (e + 4 <= end) {
        int2 p[4]; unsigned short y[4];
        #pragma unroll
        for (int j = 0; j < 4; ++j) p[j] = csr[e + j];
        #pragma unroll
        for (int j = 0; j < 4; ++j) y[j] = Y[(size_t)p[j].x * 64 + lane];
        #pragma unroll
        for (int j = 0; j < 4; ++j)
            a = fmaf(__int_as_float(p[j].y),
                     __uint_as_float(((unsigned)y[j]) << 16), a);
        e += 4;
    }
    for (; e < end; ++e) {
        int2 p = csr[e];
        a = fmaf(__int_as_float(p.y),
                 __uint_as_float(((unsigned)Y[(size_t)p.x * 64 + lane]) << 16), a);
    }

    float bs = b[lane] + b[64 + lane] + b[128 + lane];
    out[(size_t)wid * 64 + lane] = a + bs;
}

extern "C" void kernel_launch(void* const* d_in, const int* in_sizes, int n_in,
                              void* d_out, int out_size, void* d_ws, size_t ws_size,
                              hipStream_t stream)
{
    const float* x   = (const float*)d_in[0];   // [N,128]
    const float* W1  = (const float*)d_in[1];   // [3,128,128]
    const float* b1  = (const float*)d_in[2];   // [3,128]
    const float* W2  = (const float*)d_in[3];   // [3,128,64]
    const float* b2  = (const float*)d_in[4];   // [3,64]
    const int*   src = (const int*)d_in[5];     // [3,E]
    const int*   dst = (const int*)d_in[6];     // [3,E]
    float*       out = (float*)d_out;           // [N,64]

    // workspace layout
    char* w = (char*)d_ws;
    float* onorm  = (float*)w;                 w += (size_t)RN * 4;
    float* inorm  = (float*)w;                 w += (size_t)RN * 4;
    int*   off    = (int*)w;                   w += (size_t)(N_NODES + 1) * 4;
    int*   cursor = (int*)w;                   w += (size_t)N_NODES * 4;
    int*   bsums  = (int*)w;                   w += 1024;
    w = (char*)(((uintptr_t)w + 255) & ~(uintptr_t)255);
    int2*  csr    = (int2*)w;                  w += (size_t)RE * 8;
    unsigned* hbf = (unsigned*)w;              w += (size_t)N_NODES * 64 * 4;   // bf16 h [N,128]
    unsigned short* Ybf = (unsigned short*)w;  w += (size_t)N_REL * N_NODES * 128 * 2;
    unsigned short* Wt1 = (unsigned short*)w;  w += (size_t)N_REL * 128 * 128 * 2;
    unsigned short* Wt2 = (unsigned short*)w;  // 3*64*128*2

    const int SCAN_BLOCKS = (N_NODES + 1023) / 1024;   // 49
    const int mtiles = (N_NODES + 63) / 64;            // 782

    // 0) weight convert to fragment-linear bf16 (tiny)
    wtrans_kernel<<<(3 * 128 * 128 + 255) / 256, 256, 0, stream>>>(W1, Wt1, 128, 3 * 128 * 128);
    wtrans_kernel<<<(3 * 128 * 64 + 255) / 256, 256, 0, stream>>>(W2, Wt2, 64, 3 * 128 * 64);

    // 1) degrees
    hipMemsetAsync(onorm, 0, (size_t)2 * RN * 4, stream);
    deg_count_kernel<<<(RE + 255) / 256, 256, 0, stream>>>(src, dst, onorm, inorm);

    // 2) CSR offsets from combined in-degree (before norm overwrites counts)
    scan1_kernel<<<SCAN_BLOCKS, 256, 0, stream>>>(inorm, off, bsums);
    scan2_kernel<<<1, 256, 0, stream>>>(bsums, SCAN_BLOCKS);
    scan3_kernel<<<SCAN_BLOCKS, 256, 0, stream>>>(off, cursor, bsums);

    // 3) norms, then CSR fill (weight folds inorm*onorm; index folds relation)
    norm_kernel<<<(RN + 255) / 256, 256, 0, stream>>>(onorm, inorm);
    fill_kernel<<<dim3((N_EDGE + 255) / 256, N_REL), 256, 0, stream>>>(
        src, dst, onorm, inorm, cursor, csr);

    // 4) layer 1: Y_r = x @ W1_r (bf16, MFMA), gather-aggregate + bias + ReLU -> hbf (bf16)
    gemm_mfma<false, 128><<<mtiles, 256, 0, stream>>>(x, Wt1, Ybf, N_NODES);
    agg128_kernel<<<(N_NODES + 3) / 4, 256, 0, stream>>>((const unsigned*)Ybf, csr, off, b1, hbf);

    // 5) layer 2: Y_r = hbf @ W2_r (bf16, MFMA), gather-aggregate into out
    gemm_mfma<true, 64><<<mtiles, 256, 0, stream>>>(hbf, Wt2, Ybf, N_NODES);
    agg64_kernel<<<(N_NODES + 3) / 4, 256, 0, stream>>>(Ybf, csr, off, b2, out);
}

// Round 7
// 290.830 us; speedup vs baseline: 1.2101x; 1.0544x over previous
//
#include <hip/hip_runtime.h>

#define N_NODES 50000
#define N_REL   3
#define N_EDGE  200000
#define RN      (N_REL * N_NODES)      // 150000 (relation, node) pairs for norms
#define RE      (N_REL * N_EDGE)       // 600000 edges total
#define GEMM1_BLKS 782                 // ceil(50000/64)
#define DEG_BLKS   2344                // ceil(RE/256)
#define SCAN_BLOCKS 49                 // ceil(N_NODES/1024)
// dims: DIN=128, DHID=128, DOUT=64 (GEMM K is always 128)

typedef short bf16x8 __attribute__((ext_vector_type(8)));
typedef float f32x4  __attribute__((ext_vector_type(4)));

// ---------------- f32 -> bf16 (RNE) ----------------
__device__ __forceinline__ unsigned short f2bf(float f) {
    unsigned u = __float_as_uint(f);
    u = (u + 0x7fffu + ((u >> 16) & 1u)) >> 16;
    return (unsigned short)u;
}
__device__ __forceinline__ unsigned pack_bf2(float lo, float hi) {
    return (unsigned)f2bf(lo) | ((unsigned)f2bf(hi) << 16);
}

// ---------------- fused W1+W2 -> fragment-linear bf16 ----------------
// B element (rel, k, n):  frag f = (rel*(ncols/16) + n/16)*4 + k/32
// ushort idx = f*512 + ((k&31)/8)*128 + (n&15)*8 + (k&7)
__device__ __forceinline__ void wtrans_one(
    const float* __restrict__ W, unsigned short* __restrict__ Wtf, int ncols, int i)
{
    int rel = i / (128 * ncols);
    int rem = i - rel * 128 * ncols;
    int k   = rem / ncols;
    int n   = rem - k * ncols;
    int f   = (rel * (ncols / 16) + (n >> 4)) * 4 + (k >> 5);
    int idx = f * 512 + ((k & 31) >> 3) * 128 + (n & 15) * 8 + (k & 7);
    Wtf[idx] = f2bf(W[i]);
}

__global__ __launch_bounds__(256) void wtrans2_kernel(
    const float* __restrict__ W1, unsigned short* __restrict__ Wt1,
    const float* __restrict__ W2, unsigned short* __restrict__ Wt2)
{
    int i = blockIdx.x * 256 + threadIdx.x;
    if (i < 3 * 128 * 128) {
        wtrans_one(W1, Wt1, 128, i);
    } else {
        int j = i - 3 * 128 * 128;
        if (j < 3 * 128 * 64) wtrans_one(W2, Wt2, 64, j);
    }
}

// ---------------- GEMM body: Y[rel][row][0:NCOLS] = A[row,0:128] @ W[rel] ----------------
// 64-row strip; 4 waves; wave w owns rows w*16..w*16+15, walks all 64-col groups.
// B staged per-group in LDS (fragment-linear, double-buffered, issue-early/write-late).
// Stores grouped so each row's 128B line is covered by adjacent stores (write-clean).
// D layout: col=lane&15, row=(lane>>4)*4+reg (m89-verified).
template <bool ABF16, int NCOLS>
__device__ __forceinline__ void gemm_body(
    const void* __restrict__ Av, const unsigned short* __restrict__ Wtf,
    unsigned short* __restrict__ Y, int nrows, int mt,
    unsigned* As, unsigned* Ws0, unsigned* Ws1)
{
    const int tid = threadIdx.x;
    const uint4* Wt4 = (const uint4*)Wtf;

    // ---- stage A ----
    if constexpr (ABF16) {
        const uint4* Ab = (const uint4*)Av;     // bf16 rows of 128 = 16 uint4
        #pragma unroll
        for (int p = 0; p < 4; ++p) {
            int q   = p * 256 + tid;
            int row = q >> 4, w4 = q & 15;
            int gr  = mt + row;
            uint4 v = make_uint4(0u, 0u, 0u, 0u);
            if (gr < nrows) v = Ab[(size_t)gr * 16 + w4];
            As[row * 68 + w4 * 4 + 0] = v.x;
            As[row * 68 + w4 * 4 + 1] = v.y;
            As[row * 68 + w4 * 4 + 2] = v.z;
            As[row * 68 + w4 * 4 + 3] = v.w;
        }
    } else {
        const float* A = (const float*)Av;
        #pragma unroll
        for (int p = 0; p < 16; ++p) {
            int q   = tid + p * 256;
            int row = q >> 6, wc = q & 63;
            int gr  = mt + row;
            float2 v = make_float2(0.f, 0.f);
            if (gr < nrows) v = *reinterpret_cast<const float2*>(&A[(size_t)gr * 128 + wc * 2]);
            As[row * 68 + wc] = pack_bf2(v.x, v.y);
        }
    }

    // ---- stage W group 0 ----
    #pragma unroll
    for (int p = 0; p < 4; ++p) {
        uint4 v = Wt4[tid + p * 256];
        *reinterpret_cast<uint4*>(&Ws0[(tid + p * 256) * 4]) = v;
    }
    __syncthreads();

    const int w  = tid >> 6;
    const int l  = tid & 63;
    const int g  = l >> 4;
    const int lr = l & 15;
    const int ar = w * 16 + lr;

    bf16x8 a[4];
    #pragma unroll
    for (int kb = 0; kb < 4; ++kb)
        a[kb] = *reinterpret_cast<const bf16x8*>(&As[ar * 68 + kb * 16 + g * 4]);

    constexpr int TPR  = NCOLS / 16;     // 16-col tiles per relation
    constexpr int NGRP = 3 * NCOLS / 64; // 64-col groups total (6 or 3)
    const int boff = (g * 16 + lr) * 4;  // lane's word offset within a frag

    unsigned* wc_buf = Ws0;
    unsigned* wn_buf = Ws1;
    #pragma unroll 1
    for (int grp = 0; grp < NGRP; ++grp) {
        // issue next group's global loads early (latency hides under MFMA)
        uint4 st[4];
        if (grp + 1 < NGRP) {
            #pragma unroll
            for (int p = 0; p < 4; ++p)
                st[p] = Wt4[(grp + 1) * 1024 + tid + p * 256];
        }

        // compute this group: 4 x 16-col tiles
        f32x4 acc[4];
        #pragma unroll
        for (int ct4 = 0; ct4 < 4; ++ct4) {
            acc[ct4] = (f32x4){0.f, 0.f, 0.f, 0.f};
            #pragma unroll
            for (int kb = 0; kb < 4; ++kb) {
                bf16x8 b = *reinterpret_cast<const bf16x8*>(
                    &wc_buf[(ct4 * 4 + kb) * 256 + boff]);
                acc[ct4] = __builtin_amdgcn_mfma_f32_16x16x32_bf16(a[kb], b, acc[ct4], 0, 0, 0);
            }
        }

        // stores: per output row, 4 adjacent 32B stores cover the 128B line
        int gct0 = grp * 4;
        int rel  = gct0 / TPR;
        int cb   = (gct0 % TPR) * 16;
        #pragma unroll
        for (int i = 0; i < 4; ++i) {
            int grow = mt + w * 16 + g * 4 + i;
            if (grow < nrows) {
                size_t rowbase = ((size_t)rel * N_NODES + grow) * NCOLS + cb;
                #pragma unroll
                for (int ct4 = 0; ct4 < 4; ++ct4)
                    Y[rowbase + ct4 * 16 + lr] = f2bf(acc[ct4][i]);
            }
        }

        // write-late: commit the prefetched group to the other buffer
        if (grp + 1 < NGRP) {
            #pragma unroll
            for (int p = 0; p < 4; ++p)
                *reinterpret_cast<uint4*>(&wn_buf[(tid + p * 256) * 4]) = st[p];
        }
        __syncthreads();
        unsigned* t = wc_buf; wc_buf = wn_buf; wn_buf = t;
    }
}

// ---------------- FUSED: layer-1 GEMM (blocks 0..781) + degree count (rest) ----------------
// gemm1 depends only on x/Wt1; deg blocks are atomic-latency-bound (VALU ~0.4%),
// so the MFMA blocks ride along inside the same dispatch window.
__global__ __launch_bounds__(256) void fused_gemm1_deg(
    const float* __restrict__ x, const unsigned short* __restrict__ Wt1,
    unsigned short* __restrict__ Y,
    const int* __restrict__ src, const int* __restrict__ dst,
    float* __restrict__ odeg, float* __restrict__ ideg)
{
    __shared__ unsigned As[64 * 68];
    __shared__ unsigned Ws[2][4096];

    if (blockIdx.x < GEMM1_BLKS) {
        gemm_body<false, 128>(x, Wt1, Y, N_NODES, blockIdx.x * 64, As, Ws[0], Ws[1]);
    } else {
        int i = (blockIdx.x - GEMM1_BLKS) * 256 + threadIdx.x;
        if (i < RE) {
            int r = i / N_EDGE;
            unsafeAtomicAdd(&odeg[r * N_NODES + src[i]], 1.0f);
            unsafeAtomicAdd(&ideg[r * N_NODES + dst[i]], 1.0f);
        }
    }
}

// ---------------- standalone GEMM (layer 2) ----------------
template <bool ABF16, int NCOLS>
__global__ __launch_bounds__(256) void gemm_mfma(
    const void* __restrict__ Av, const unsigned short* __restrict__ Wtf,
    unsigned short* __restrict__ Y, int nrows)
{
    __shared__ unsigned As[64 * 68];
    __shared__ unsigned Ws[2][4096];
    gemm_body<ABF16, NCOLS>(Av, Wtf, Y, nrows, blockIdx.x * 64, As, Ws[0], Ws[1]);
}

// ---------------- exclusive scan over N_NODES combined in-degree (sum of 3 rels) ----------------
__global__ __launch_bounds__(256) void scan1_kernel(
    const float* __restrict__ ideg, int* __restrict__ off, int* __restrict__ bsums)
{
    __shared__ int tsum[256];
    int tid  = threadIdx.x;
    int base = blockIdx.x * 1024 + tid * 4;
    int c[4], s = 0;
    #pragma unroll
    for (int j = 0; j < 4; ++j) {
        int idx = base + j;
        c[j] = (idx < N_NODES)
             ? (int)(ideg[idx] + ideg[N_NODES + idx] + ideg[2 * N_NODES + idx]) : 0;
        s += c[j];
    }
    tsum[tid] = s;
    __syncthreads();
    #pragma unroll
    for (int d = 1; d < 256; d <<= 1) {
        int v   = tsum[tid];
        int add = (tid >= d) ? tsum[tid - d] : 0;
        __syncthreads();
        tsum[tid] = v + add;
        __syncthreads();
    }
    int run = tsum[tid] - s;
    #pragma unroll
    for (int j = 0; j < 4; ++j) {
        if (base + j < N_NODES) off[base + j] = run;
        run += c[j];
    }
    if (tid == 255) bsums[blockIdx.x] = tsum[255];
}

__global__ __launch_bounds__(256) void scan2_kernel(int* __restrict__ bsums, int nb)
{
    __shared__ int t[256];
    int tid = threadIdx.x;
    int v0  = (tid < nb) ? bsums[tid] : 0;
    t[tid] = v0;
    __syncthreads();
    #pragma unroll
    for (int d = 1; d < 256; d <<= 1) {
        int v   = t[tid];
        int add = (tid >= d) ? t[tid - d] : 0;
        __syncthreads();
        t[tid] = v + add;
        __syncthreads();
    }
    if (tid < nb) bsums[tid] = t[tid] - v0;
}

// scan3 + norm fused (norm runs after scan1 consumed the raw counts)
__global__ __launch_bounds__(256) void scan3_kernel(
    int* __restrict__ off, int* __restrict__ cursor, const int* __restrict__ bsums,
    float* __restrict__ odeg, float* __restrict__ ideg)
{
    int tid  = threadIdx.x;
    int base = blockIdx.x * 1024 + tid * 4;
    int add  = bsums[blockIdx.x];
    #pragma unroll
    for (int j = 0; j < 4; ++j) {
        if (base + j < N_NODES) {
            int v = off[base + j] + add;
            off[base + j]    = v;
            cursor[base + j] = v;
        }
    }
    if (blockIdx.x == 0 && tid == 0) off[N_NODES] = RE;

    // fold: counts -> norms
    int t = blockIdx.x * 256 + tid;
    for (int q = t; q < RN; q += SCAN_BLOCKS * 256) {
        odeg[q] = rsqrtf(fmaxf(odeg[q], 1.0f));
        ideg[q] = rsqrtf(fmaxf(ideg[q], 1.0f));
    }
}

// ---------------- CSR fill: bin by dst; payload = (r*N+src, onorm[r][src]*inorm[r][dst]) ----------------
__global__ __launch_bounds__(256) void fill_kernel(
    const int* __restrict__ src, const int* __restrict__ dst,
    const float* __restrict__ onorm, const float* __restrict__ inorm,
    int* __restrict__ cursor, int2* __restrict__ csr)
{
    int i = blockIdx.x * 256 + threadIdx.x;
    if (i >= N_EDGE) return;
    int r = blockIdx.y;
    int s = src[r * N_EDGE + i];
    int t = dst[r * N_EDGE + i];
    float wv = onorm[r * N_NODES + s] * inorm[r * N_NODES + t];
    int pos = atomicAdd(&cursor[t], 1);
    csr[pos] = make_int2(r * N_NODES + s, __float_as_int(wv));
}

// ---------------- gather aggregation, layer 1 (D=128), fused CSR, unroll-8 ----------------
__global__ __launch_bounds__(256) void agg128_kernel(
    const unsigned* __restrict__ Y, const int2* __restrict__ csr,
    const int* __restrict__ off, const float* __restrict__ b, unsigned* __restrict__ hbf)
{
    int wid  = (blockIdx.x * 256 + threadIdx.x) >> 6;
    int lane = threadIdx.x & 63;
    if (wid >= N_NODES) return;

    int e = off[wid], end = off[wid + 1];
    float a0 = 0.f, a1 = 0.f;

    for (; e + 8 <= end; e += 8) {
        int2 p[8]; unsigned y[8];
        #pragma unroll
        for (int j = 0; j < 8; ++j) p[j] = csr[e + j];
        #pragma unroll
        for (int j = 0; j < 8; ++j) y[j] = Y[(size_t)p[j].x * 64 + lane];
        #pragma unroll
        for (int j = 0; j < 8; ++j) {
            float wv = __int_as_float(p[j].y);
            a0 = fmaf(wv, __uint_as_float(y[j] << 16), a0);
            a1 = fmaf(wv, __uint_as_float(y[j] & 0xffff0000u), a1);
        }
    }
    if (e + 4 <= end) {
        int2 p[4]; unsigned y[4];
        #pragma unroll
        for (int j = 0; j < 4; ++j) p[j] = csr[e + j];
        #pragma unroll
        for (int j = 0; j < 4; ++j) y[j] = Y[(size_t)p[j].x * 64 + lane];
        #pragma unroll
        for (int j = 0; j < 4; ++j) {
            float wv = __int_as_float(p[j].y);
            a0 = fmaf(wv, __uint_as_float(y[j] << 16), a0);
            a1 = fmaf(wv, __uint_as_float(y[j] & 0xffff0000u), a1);
        }
        e += 4;
    }
    for (; e < end; ++e) {
        int2 p = csr[e];
        float wv = __int_as_float(p.y);
        unsigned y = Y[(size_t)p.x * 64 + lane];
        a0 = fmaf(wv, __uint_as_float(y << 16), a0);
        a1 = fmaf(wv, __uint_as_float(y & 0xffff0000u), a1);
    }

    int d = lane * 2;
    float o0 = a0 + b[d]     + b[128 + d]     + b[256 + d];
    float o1 = a1 + b[d + 1] + b[128 + d + 1] + b[256 + d + 1];
    hbf[(size_t)wid * 64 + lane] = pack_bf2(fmaxf(o0, 0.f), fmaxf(o1, 0.f));
}

// ---------------- gather aggregation, layer 2 (D=64), fused CSR, unroll-8 ----------------
__global__ __launch_bounds__(256) void agg64_kernel(
    const unsigned short* __restrict__ Y, const int2* __restrict__ csr,
    const int* __restrict__ off, const float* __restrict__ b, float* __restrict__ out)
{
    int wid  = (blockIdx.x * 256 + threadIdx.x) >> 6;
    int lane = threadIdx.x & 63;
    if (wid >= N_NODES) return;

    int e = off[wid], end = off[wid + 1];
    float a = 0.f;

    for (; e + 8 <= end; e += 8) {
        int2 p[8]; unsigned short y[8];
        #pragma unroll
        for (int j = 0; j < 8; ++j) p[j] = csr[e + j];
        #pragma unroll
        for (int j = 0; j < 8; ++j) y[j] = Y[(size_t)p[j].x * 64 + lane];
        #pragma unroll
        for (int j = 0; j < 8; ++j)
            a = fmaf(__int_as_float(p[j].y),
                     __uint_as_float(((unsigned)y[j]) << 16), a);
    }
    if (e + 4 <= end) {
        int2 p[4]; unsigned short y[4];
        #pragma unroll
        for (int j = 0; j < 4; ++j) p[j] = csr[e + j];
        #pragma unroll
        for (int j = 0; j < 4; ++j) y[j] = Y[(size_t)p[j].x * 64 + lane];
        #pragma unroll
        for (int j = 0; j < 4; ++j)
            a = fmaf(__int_as_float(p[j].y),
                     __uint_as_float(((unsigned)y[j]) << 16), a);
        e += 4;
    }
    for (; e < end; ++e) {
        int2 p = csr[e];
        a = fmaf(__int_as_float(p.y),
                 __uint_as_float(((unsigned)Y[(size_t)p.x * 64 + lane]) << 16), a);
    }

    float bs = b[lane] + b[64 + lane] + b[128 + lane];
    out[(size_t)wid * 64 + lane] = a + bs;
}

extern "C" void kernel_launch(void* const* d_in, const int* in_sizes, int n_in,
                              void* d_out, int out_size, void* d_ws, size_t ws_size,
                              hipStream_t stream)
{
    const float* x   = (const float*)d_in[0];   // [N,128]
    const float* W1  = (const float*)d_in[1];   // [3,128,128]
    const float* b1  = (const float*)d_in[2];   // [3,128]
    const float* W2  = (const float*)d_in[3];   // [3,128,64]
    const float* b2  = (const float*)d_in[4];   // [3,64]
    const int*   src = (const int*)d_in[5];     // [3,E]
    const int*   dst = (const int*)d_in[6];     // [3,E]
    float*       out = (float*)d_out;           // [N,64]

    // workspace layout
    char* w = (char*)d_ws;
    float* onorm  = (float*)w;                 w += (size_t)RN * 4;
    float* inorm  = (float*)w;                 w += (size_t)RN * 4;
    int*   off    = (int*)w;                   w += (size_t)(N_NODES + 1) * 4;
    int*   cursor = (int*)w;                   w += (size_t)N_NODES * 4;
    int*   bsums  = (int*)w;                   w += 1024;
    w = (char*)(((uintptr_t)w + 255) & ~(uintptr_t)255);
    int2*  csr    = (int2*)w;                  w += (size_t)RE * 8;
    unsigned* hbf = (unsigned*)w;              w += (size_t)N_NODES * 64 * 4;   // bf16 h [N,128]
    unsigned short* Ybf = (unsigned short*)w;  w += (size_t)N_REL * N_NODES * 128 * 2;
    unsigned short* Wt1 = (unsigned short*)w;  w += (size_t)N_REL * 128 * 128 * 2;
    unsigned short* Wt2 = (unsigned short*)w;  // 3*64*128*2

    // 0) weight convert (one kernel) — must precede fused gemm1
    wtrans2_kernel<<<(3 * 128 * 128 + 3 * 128 * 64 + 255) / 256, 256, 0, stream>>>(
        W1, Wt1, W2, Wt2);

    // 1) zero degree counters, then FUSED: gemm1 (x@W1 -> Ybf) + degree count
    hipMemsetAsync(onorm, 0, (size_t)2 * RN * 4, stream);
    fused_gemm1_deg<<<GEMM1_BLKS + DEG_BLKS, 256, 0, stream>>>(
        x, Wt1, Ybf, src, dst, onorm, inorm);

    // 2) CSR offsets from combined in-degree; scan3 also converts counts -> norms
    scan1_kernel<<<SCAN_BLOCKS, 256, 0, stream>>>(inorm, off, bsums);
    scan2_kernel<<<1, 256, 0, stream>>>(bsums, SCAN_BLOCKS);
    scan3_kernel<<<SCAN_BLOCKS, 256, 0, stream>>>(off, cursor, bsums, onorm, inorm);

    // 3) CSR fill (weight folds inorm*onorm; index folds relation)
    fill_kernel<<<dim3((N_EDGE + 255) / 256, N_REL), 256, 0, stream>>>(
        src, dst, onorm, inorm, cursor, csr);

    // 4) layer 1 aggregate + bias + ReLU -> hbf (bf16)
    agg128_kernel<<<(N_NODES + 3) / 4, 256, 0, stream>>>((const unsigned*)Ybf, csr, off, b1, hbf);

    // 5) layer 2: Y_r = hbf @ W2_r (bf16, MFMA), gather-aggregate into out
    gemm_mfma<true, 64><<<GEMM1_BLKS, 256, 0, stream>>>(hbf, Wt2, Ybf, N_NODES);
    agg64_kernel<<<(N_NODES + 3) / 4, 256, 0, stream>>>(Ybf, csr, off, b2, out);
}

// Round 8
// 264.357 us; speedup vs baseline: 1.3313x; 1.1001x over previous
//
#include <hip/hip_runtime.h>

#define N_NODES 50000
#define N_REL   3
#define N_EDGE  200000
#define RN      (N_REL * N_NODES)      // 150000 (relation, node) pairs for norms
#define RE      (N_REL * N_EDGE)       // 600000 edges total
#define GEMM1_BLKS 782                 // ceil(50000/64)
#define DEG_BLKS   2344                // ceil(RE/256)
#define SCAN_BLOCKS 49                 // ceil(N_NODES/1024)
#define FUSE_CHUNKS 98                 // 98*8=784>=782 gemm, 98*24=2352>=2344 deg
// dims: DIN=128, DHID=128, DOUT=64 (GEMM K is always 128)

typedef short bf16x8 __attribute__((ext_vector_type(8)));
typedef float f32x4  __attribute__((ext_vector_type(4)));

// ---------------- f32 -> bf16 (RNE) ----------------
__device__ __forceinline__ unsigned short f2bf(float f) {
    unsigned u = __float_as_uint(f);
    u = (u + 0x7fffu + ((u >> 16) & 1u)) >> 16;
    return (unsigned short)u;
}
__device__ __forceinline__ unsigned pack_bf2(float lo, float hi) {
    return (unsigned)f2bf(lo) | ((unsigned)f2bf(hi) << 16);
}

// ---------------- fused W1+W2 -> fragment-linear bf16 ----------------
// B element (rel, k, n):  frag f = (rel*(ncols/16) + n/16)*4 + k/32
// ushort idx = f*512 + ((k&31)/8)*128 + (n&15)*8 + (k&7)
__device__ __forceinline__ void wtrans_one(
    const float* __restrict__ W, unsigned short* __restrict__ Wtf, int ncols, int i)
{
    int rel = i / (128 * ncols);
    int rem = i - rel * 128 * ncols;
    int k   = rem / ncols;
    int n   = rem - k * ncols;
    int f   = (rel * (ncols / 16) + (n >> 4)) * 4 + (k >> 5);
    int idx = f * 512 + ((k & 31) >> 3) * 128 + (n & 15) * 8 + (k & 7);
    Wtf[idx] = f2bf(W[i]);
}

__global__ __launch_bounds__(256) void wtrans2_kernel(
    const float* __restrict__ W1, unsigned short* __restrict__ Wt1,
    const float* __restrict__ W2, unsigned short* __restrict__ Wt2)
{
    int i = blockIdx.x * 256 + threadIdx.x;
    if (i < 3 * 128 * 128) {
        wtrans_one(W1, Wt1, 128, i);
    } else {
        int j = i - 3 * 128 * 128;
        if (j < 3 * 128 * 64) wtrans_one(W2, Wt2, 64, j);
    }
}

// ---------------- heavy GEMM body (layer 2, standalone): A staged in LDS, W dbuf ----------------
template <bool ABF16, int NCOLS>
__device__ __forceinline__ void gemm_body(
    const void* __restrict__ Av, const unsigned short* __restrict__ Wtf,
    unsigned short* __restrict__ Y, int nrows, int mt,
    unsigned* As, unsigned* Ws0, unsigned* Ws1)
{
    const int tid = threadIdx.x;
    const uint4* Wt4 = (const uint4*)Wtf;

    if constexpr (ABF16) {
        const uint4* Ab = (const uint4*)Av;
        #pragma unroll
        for (int p = 0; p < 4; ++p) {
            int q   = p * 256 + tid;
            int row = q >> 4, w4 = q & 15;
            int gr  = mt + row;
            uint4 v = make_uint4(0u, 0u, 0u, 0u);
            if (gr < nrows) v = Ab[(size_t)gr * 16 + w4];
            As[row * 68 + w4 * 4 + 0] = v.x;
            As[row * 68 + w4 * 4 + 1] = v.y;
            As[row * 68 + w4 * 4 + 2] = v.z;
            As[row * 68 + w4 * 4 + 3] = v.w;
        }
    } else {
        const float* A = (const float*)Av;
        #pragma unroll
        for (int p = 0; p < 16; ++p) {
            int q   = tid + p * 256;
            int row = q >> 6, wc = q & 63;
            int gr  = mt + row;
            float2 v = make_float2(0.f, 0.f);
            if (gr < nrows) v = *reinterpret_cast<const float2*>(&A[(size_t)gr * 128 + wc * 2]);
            As[row * 68 + wc] = pack_bf2(v.x, v.y);
        }
    }

    #pragma unroll
    for (int p = 0; p < 4; ++p) {
        uint4 v = Wt4[tid + p * 256];
        *reinterpret_cast<uint4*>(&Ws0[(tid + p * 256) * 4]) = v;
    }
    __syncthreads();

    const int w  = tid >> 6;
    const int l  = tid & 63;
    const int g  = l >> 4;
    const int lr = l & 15;
    const int ar = w * 16 + lr;

    bf16x8 a[4];
    #pragma unroll
    for (int kb = 0; kb < 4; ++kb)
        a[kb] = *reinterpret_cast<const bf16x8*>(&As[ar * 68 + kb * 16 + g * 4]);

    constexpr int TPR  = NCOLS / 16;
    constexpr int NGRP = 3 * NCOLS / 64;
    const int boff = (g * 16 + lr) * 4;

    unsigned* wc_buf = Ws0;
    unsigned* wn_buf = Ws1;
    #pragma unroll 1
    for (int grp = 0; grp < NGRP; ++grp) {
        uint4 st[4];
        if (grp + 1 < NGRP) {
            #pragma unroll
            for (int p = 0; p < 4; ++p)
                st[p] = Wt4[(grp + 1) * 1024 + tid + p * 256];
        }

        f32x4 acc[4];
        #pragma unroll
        for (int ct4 = 0; ct4 < 4; ++ct4) {
            acc[ct4] = (f32x4){0.f, 0.f, 0.f, 0.f};
            #pragma unroll
            for (int kb = 0; kb < 4; ++kb) {
                bf16x8 b = *reinterpret_cast<const bf16x8*>(
                    &wc_buf[(ct4 * 4 + kb) * 256 + boff]);
                acc[ct4] = __builtin_amdgcn_mfma_f32_16x16x32_bf16(a[kb], b, acc[ct4], 0, 0, 0);
            }
        }

        int gct0 = grp * 4;
        int rel  = gct0 / TPR;
        int cb   = (gct0 % TPR) * 16;
        #pragma unroll
        for (int i = 0; i < 4; ++i) {
            int grow = mt + w * 16 + g * 4 + i;
            if (grow < nrows) {
                size_t rowbase = ((size_t)rel * N_NODES + grow) * NCOLS + cb;
                #pragma unroll
                for (int ct4 = 0; ct4 < 4; ++ct4)
                    Y[rowbase + ct4 * 16 + lr] = f2bf(acc[ct4][i]);
            }
        }

        if (grp + 1 < NGRP) {
            #pragma unroll
            for (int p = 0; p < 4; ++p)
                *reinterpret_cast<uint4*>(&wn_buf[(tid + p * 256) * 4]) = st[p];
        }
        __syncthreads();
        unsigned* t = wc_buf; wc_buf = wn_buf; wn_buf = t;
    }
}

template <bool ABF16, int NCOLS>
__global__ __launch_bounds__(256) void gemm_mfma(
    const void* __restrict__ Av, const unsigned short* __restrict__ Wtf,
    unsigned short* __restrict__ Y, int nrows)
{
    __shared__ unsigned As[64 * 68];
    __shared__ unsigned Ws[2][4096];
    gemm_body<ABF16, NCOLS>(Av, Wtf, Y, nrows, blockIdx.x * 64, As, Ws[0], Ws[1]);
}

// ---------------- LDS-light layer-1 GEMM body (16KB LDS total, for fusion) ----------------
// A-frags loaded directly from global f32 (rows coalesce at 128B chunks, x read once),
// W single-buffered in LDS. Keeps write-clean store grouping.
__device__ __forceinline__ void gemm1_body_light(
    const float* __restrict__ A, const unsigned short* __restrict__ Wtf,
    unsigned short* __restrict__ Y, int mt, unsigned* Ws)
{
    const int tid = threadIdx.x;
    const uint4* Wt4 = (const uint4*)Wtf;
    const int w  = tid >> 6;
    const int l  = tid & 63;
    const int g  = l >> 4;
    const int lr = l & 15;
    const int arow = mt + w * 16 + lr;
    const bool rowok = arow < N_NODES;

    bf16x8 a[4];
    #pragma unroll
    for (int kb = 0; kb < 4; ++kb) {
        float4 v0 = make_float4(0.f, 0.f, 0.f, 0.f);
        float4 v1 = make_float4(0.f, 0.f, 0.f, 0.f);
        if (rowok) {
            const float* ap = &A[(size_t)arow * 128 + kb * 32 + g * 8];
            v0 = *reinterpret_cast<const float4*>(ap);
            v1 = *reinterpret_cast<const float4*>(ap + 4);
        }
        union { unsigned u[4]; bf16x8 v; } cv;
        cv.u[0] = pack_bf2(v0.x, v0.y);
        cv.u[1] = pack_bf2(v0.z, v0.w);
        cv.u[2] = pack_bf2(v1.x, v1.y);
        cv.u[3] = pack_bf2(v1.z, v1.w);
        a[kb] = cv.v;
    }

    const int boff = (g * 16 + lr) * 4;

    #pragma unroll 1
    for (int grp = 0; grp < 6; ++grp) {           // 6 groups: rel = grp/2, cols (grp&1)*64
        __syncthreads();                           // prior group's reads complete
        #pragma unroll
        for (int p = 0; p < 4; ++p) {
            uint4 v = Wt4[grp * 1024 + tid + p * 256];
            *reinterpret_cast<uint4*>(&Ws[(tid + p * 256) * 4]) = v;
        }
        __syncthreads();

        f32x4 acc[4];
        #pragma unroll
        for (int ct4 = 0; ct4 < 4; ++ct4) {
            acc[ct4] = (f32x4){0.f, 0.f, 0.f, 0.f};
            #pragma unroll
            for (int kb = 0; kb < 4; ++kb) {
                bf16x8 b = *reinterpret_cast<const bf16x8*>(
                    &Ws[(ct4 * 4 + kb) * 256 + boff]);
                acc[ct4] = __builtin_amdgcn_mfma_f32_16x16x32_bf16(a[kb], b, acc[ct4], 0, 0, 0);
            }
        }

        int rel = grp >> 1;
        int cb  = (grp & 1) * 64;
        #pragma unroll
        for (int i = 0; i < 4; ++i) {
            int grow = mt + w * 16 + g * 4 + i;
            if (grow < N_NODES) {
                size_t rowbase = ((size_t)rel * N_NODES + grow) * 128 + cb;
                #pragma unroll
                for (int ct4 = 0; ct4 < 4; ++ct4)
                    Y[rowbase + ct4 * 16 + lr] = f2bf(acc[ct4][i]);
            }
        }
    }
}

// ---------------- FUSED: layer-1 GEMM + degree count + rank, chunk-interleaved ----------------
// 32-block period: 8 gemm blocks (one per XCD under mod-8 placement) + 24 deg blocks,
// so atomic-latency waves and MFMA waves are co-resident from t=0 (m114 overlap).
// deg also records each edge's rank within its (rel,dst) bin from the atomic return.
__global__ __launch_bounds__(256) void fused_gemm1_deg(
    const float* __restrict__ x, const unsigned short* __restrict__ Wt1,
    unsigned short* __restrict__ Y,
    const int* __restrict__ src, const int* __restrict__ dst,
    float* __restrict__ odeg, float* __restrict__ ideg,
    unsigned short* __restrict__ rank)
{
    __shared__ unsigned Ws[4096];    // 16KB only -> deg co-tenancy up to 8 blocks/CU

    const int c = blockIdx.x >> 5;
    const int o = blockIdx.x & 31;

    if (o < 8) {
        int gb = c * 8 + o;
        if (gb >= GEMM1_BLKS) return;
        gemm1_body_light(x, Wt1, Y, gb * 64, Ws);
    } else {
        int db = c * 24 + (o - 8);
        int i  = db * 256 + threadIdx.x;
        if (i < RE) {
            int r = i / N_EDGE;
            int s = src[i], t = dst[i];
            unsafeAtomicAdd(&odeg[r * N_NODES + s], 1.0f);
            float old = unsafeAtomicAdd(&ideg[r * N_NODES + t], 1.0f);
            rank[i] = (unsigned short)(int)old;
        }
    }
}

// ---------------- exclusive scan over N_NODES combined in-degree (sum of 3 rels) ----------------
__global__ __launch_bounds__(256) void scan1_kernel(
    const float* __restrict__ ideg, int* __restrict__ off, int* __restrict__ bsums)
{
    __shared__ int tsum[256];
    int tid  = threadIdx.x;
    int base = blockIdx.x * 1024 + tid * 4;
    int c[4], s = 0;
    #pragma unroll
    for (int j = 0; j < 4; ++j) {
        int idx = base + j;
        c[j] = (idx < N_NODES)
             ? (int)(ideg[idx] + ideg[N_NODES + idx] + ideg[2 * N_NODES + idx]) : 0;
        s += c[j];
    }
    tsum[tid] = s;
    __syncthreads();
    #pragma unroll
    for (int d = 1; d < 256; d <<= 1) {
        int v   = tsum[tid];
        int add = (tid >= d) ? tsum[tid - d] : 0;
        __syncthreads();
        tsum[tid] = v + add;
        __syncthreads();
    }
    int run = tsum[tid] - s;
    #pragma unroll
    for (int j = 0; j < 4; ++j) {
        if (base + j < N_NODES) off[base + j] = run;
        run += c[j];
    }
    if (tid == 255) bsums[blockIdx.x] = tsum[255];
}

// scan3: in-block prefix of bsums (replaces scan2) + global off + per-(r,t) segment
// bases roff + counts->norms conversion.
__global__ __launch_bounds__(256) void scan3_kernel(
    int* __restrict__ off, const int* __restrict__ bsums, int* __restrict__ roff,
    float* __restrict__ odeg, float* __restrict__ ideg)
{
    __shared__ int addsh;
    int tid = threadIdx.x;
    if (tid < 64) {
        int v = (tid < blockIdx.x) ? bsums[tid] : 0;   // blockIdx < 49 <= 64
        #pragma unroll
        for (int d = 32; d > 0; d >>= 1) v += __shfl_down(v, d, 64);
        if (tid == 0) addsh = v;
    }
    __syncthreads();
    int add = addsh;

    int base = blockIdx.x * 1024 + tid * 4;
    #pragma unroll
    for (int j = 0; j < 4; ++j) {
        int t = base + j;
        if (t < N_NODES) {
            int v = off[t] + add;
            off[t] = v;
            float c0 = ideg[t];
            float c1 = ideg[N_NODES + t];
            float c2 = ideg[2 * N_NODES + t];
            roff[t]               = v;
            roff[N_NODES + t]     = v + (int)c0;
            roff[2 * N_NODES + t] = v + (int)(c0 + c1);
            ideg[t]               = rsqrtf(fmaxf(c0, 1.0f));
            ideg[N_NODES + t]     = rsqrtf(fmaxf(c1, 1.0f));
            ideg[2 * N_NODES + t] = rsqrtf(fmaxf(c2, 1.0f));
        }
    }
    if (blockIdx.x == 0 && tid == 0) off[N_NODES] = RE;

    // out-degree counts -> norms (strided over RN)
    int q0 = blockIdx.x * 256 + tid;
    for (int q = q0; q < RN; q += SCAN_BLOCKS * 256)
        odeg[q] = rsqrtf(fmaxf(odeg[q], 1.0f));
}

// ---------------- CSR fill, atomic-free: slot = roff[r][t] + rank[e] ----------------
__global__ __launch_bounds__(256) void fill_kernel(
    const int* __restrict__ src, const int* __restrict__ dst,
    const float* __restrict__ onorm, const float* __restrict__ inorm,
    const int* __restrict__ roff, const unsigned short* __restrict__ rank,
    int2* __restrict__ csr)
{
    int i = blockIdx.x * 256 + threadIdx.x;
    if (i >= N_EDGE) return;
    int r   = blockIdx.y;
    int idx = r * N_EDGE + i;
    int s = src[idx], t = dst[idx];
    float wv = onorm[r * N_NODES + s] * inorm[r * N_NODES + t];
    int slot = roff[r * N_NODES + t] + (int)rank[idx];
    csr[slot] = make_int2(r * N_NODES + s, __float_as_int(wv));
}

// ---------------- gather aggregation, layer 1 (D=128), fused CSR, unroll-8 ----------------
__global__ __launch_bounds__(256) void agg128_kernel(
    const unsigned* __restrict__ Y, const int2* __restrict__ csr,
    const int* __restrict__ off, const float* __restrict__ b, unsigned* __restrict__ hbf)
{
    int wid  = (blockIdx.x * 256 + threadIdx.x) >> 6;
    int lane = threadIdx.x & 63;
    if (wid >= N_NODES) return;

    int e = off[wid], end = off[wid + 1];
    float a0 = 0.f, a1 = 0.f;

    for (; e + 8 <= end; e += 8) {
        int2 p[8]; unsigned y[8];
        #pragma unroll
        for (int j = 0; j < 8; ++j) p[j] = csr[e + j];
        #pragma unroll
        for (int j = 0; j < 8; ++j) y[j] = Y[(size_t)p[j].x * 64 + lane];
        #pragma unroll
        for (int j = 0; j < 8; ++j) {
            float wv = __int_as_float(p[j].y);
            a0 = fmaf(wv, __uint_as_float(y[j] << 16), a0);
            a1 = fmaf(wv, __uint_as_float(y[j] & 0xffff0000u), a1);
        }
    }
    if (e + 4 <= end) {
        int2 p[4]; unsigned y[4];
        #pragma unroll
        for (int j = 0; j < 4; ++j) p[j] = csr[e + j];
        #pragma unroll
        for (int j = 0; j < 4; ++j) y[j] = Y[(size_t)p[j].x * 64 + lane];
        #pragma unroll
        for (int j = 0; j < 4; ++j) {
            float wv = __int_as_float(p[j].y);
            a0 = fmaf(wv, __uint_as_float(y[j] << 16), a0);
            a1 = fmaf(wv, __uint_as_float(y[j] & 0xffff0000u), a1);
        }
        e += 4;
    }
    for (; e < end; ++e) {
        int2 p = csr[e];
        float wv = __int_as_float(p.y);
        unsigned y = Y[(size_t)p.x * 64 + lane];
        a0 = fmaf(wv, __uint_as_float(y << 16), a0);
        a1 = fmaf(wv, __uint_as_float(y & 0xffff0000u), a1);
    }

    int d = lane * 2;
    float o0 = a0 + b[d]     + b[128 + d]     + b[256 + d];
    float o1 = a1 + b[d + 1] + b[128 + d + 1] + b[256 + d + 1];
    hbf[(size_t)wid * 64 + lane] = pack_bf2(fmaxf(o0, 0.f), fmaxf(o1, 0.f));
}

// ---------------- gather aggregation, layer 2 (D=64), fused CSR, unroll-8 ----------------
__global__ __launch_bounds__(256) void agg64_kernel(
    const unsigned short* __restrict__ Y, const int2* __restrict__ csr,
    const int* __restrict__ off, const float* __restrict__ b, float* __restrict__ out)
{
    int wid  = (blockIdx.x * 256 + threadIdx.x) >> 6;
    int lane = threadIdx.x & 63;
    if (wid >= N_NODES) return;

    int e = off[wid], end = off[wid + 1];
    float a = 0.f;

    for (; e + 8 <= end; e += 8) {
        int2 p[8]; unsigned short y[8];
        #pragma unroll
        for (int j = 0; j < 8; ++j) p[j] = csr[e + j];
        #pragma unroll
        for (int j = 0; j < 8; ++j) y[j] = Y[(size_t)p[j].x * 64 + lane];
        #pragma unroll
        for (int j = 0; j < 8; ++j)
            a = fmaf(__int_as_float(p[j].y),
                     __uint_as_float(((unsigned)y[j]) << 16), a);
    }
    if (e + 4 <= end) {
        int2 p[4]; unsigned short y[4];
        #pragma unroll
        for (int j = 0; j < 4; ++j) p[j] = csr[e + j];
        #pragma unroll
        for (int j = 0; j < 4; ++j) y[j] = Y[(size_t)p[j].x * 64 + lane];
        #pragma unroll
        for (int j = 0; j < 4; ++j)
            a = fmaf(__int_as_float(p[j].y),
                     __uint_as_float(((unsigned)y[j]) << 16), a);
        e += 4;
    }
    for (; e < end; ++e) {
        int2 p = csr[e];
        a = fmaf(__int_as_float(p.y),
                 __uint_as_float(((unsigned)Y[(size_t)p.x * 64 + lane]) << 16), a);
    }

    float bs = b[lane] + b[64 + lane] + b[128 + lane];
    out[(size_t)wid * 64 + lane] = a + bs;
}

extern "C" void kernel_launch(void* const* d_in, const int* in_sizes, int n_in,
                              void* d_out, int out_size, void* d_ws, size_t ws_size,
                              hipStream_t stream)
{
    const float* x   = (const float*)d_in[0];   // [N,128]
    const float* W1  = (const float*)d_in[1];   // [3,128,128]
    const float* b1  = (const float*)d_in[2];   // [3,128]
    const float* W2  = (const float*)d_in[3];   // [3,128,64]
    const float* b2  = (const float*)d_in[4];   // [3,64]
    const int*   src = (const int*)d_in[5];     // [3,E]
    const int*   dst = (const int*)d_in[6];     // [3,E]
    float*       out = (float*)d_out;           // [N,64]

    // workspace layout
    char* w = (char*)d_ws;
    float* onorm  = (float*)w;                 w += (size_t)RN * 4;           // counts then norms
    float* inorm  = (float*)w;                 w += (size_t)RN * 4;           // counts then norms
    int*   off    = (int*)w;                   w += (size_t)(N_NODES + 1) * 4;
    int*   roff   = (int*)w;                   w += (size_t)RN * 4;
    int*   bsums  = (int*)w;                   w += 1024;
    unsigned short* rank = (unsigned short*)w; w += (size_t)RE * 2;
    w = (char*)(((uintptr_t)w + 255) & ~(uintptr_t)255);
    int2*  csr    = (int2*)w;                  w += (size_t)RE * 8;
    unsigned* hbf = (unsigned*)w;              w += (size_t)N_NODES * 64 * 4; // bf16 h [N,128]
    unsigned short* Ybf = (unsigned short*)w;  w += (size_t)N_REL * N_NODES * 128 * 2;
    unsigned short* Wt1 = (unsigned short*)w;  w += (size_t)N_REL * 128 * 128 * 2;
    unsigned short* Wt2 = (unsigned short*)w;  // 3*64*128*2

    // 0) weight convert (one kernel) — must precede fused gemm1
    wtrans2_kernel<<<(3 * 128 * 128 + 3 * 128 * 64 + 255) / 256, 256, 0, stream>>>(
        W1, Wt1, W2, Wt2);

    // 1) zero degree counters, then FUSED interleaved: gemm1 (x@W1 -> Ybf) + degrees + ranks
    hipMemsetAsync(onorm, 0, (size_t)2 * RN * 4, stream);
    fused_gemm1_deg<<<FUSE_CHUNKS * 32, 256, 0, stream>>>(
        x, Wt1, Ybf, src, dst, onorm, inorm, rank);

    // 2) CSR offsets: scan1 -> scan3 (scan3 does block-prefix, roff, norms)
    scan1_kernel<<<SCAN_BLOCKS, 256, 0, stream>>>(inorm, off, bsums);
    scan3_kernel<<<SCAN_BLOCKS, 256, 0, stream>>>(off, bsums, roff, onorm, inorm);

    // 3) CSR fill (atomic-free: slot = roff + rank)
    fill_kernel<<<dim3((N_EDGE + 255) / 256, N_REL), 256, 0, stream>>>(
        src, dst, onorm, inorm, roff, rank, csr);

    // 4) layer 1 aggregate + bias + ReLU -> hbf (bf16)
    agg128_kernel<<<(N_NODES + 3) / 4, 256, 0, stream>>>((const unsigned*)Ybf, csr, off, b1, hbf);

    // 5) layer 2: Y_r = hbf @ W2_r (bf16, MFMA), gather-aggregate into out
    gemm_mfma<true, 64><<<GEMM1_BLKS, 256, 0, stream>>>(hbf, Wt2, Ybf, N_NODES);
    agg64_kernel<<<(N_NODES + 3) / 4, 256, 0, stream>>>(Ybf, csr, off, b2, out);
}

// Round 9
// 261.160 us; speedup vs baseline: 1.3476x; 1.0122x over previous
//
#include <hip/hip_runtime.h>

#define N_NODES 50000
#define N_REL   3
#define N_EDGE  200000
#define RN      (N_REL * N_NODES)      // 150000 (relation, node) pairs for norms
#define RE      (N_REL * N_EDGE)       // 600000 edges total
#define GEMM1_BLKS 782                 // ceil(50000/64)
#define DEG_BLKS   2344                // ceil(RE/256)
#define SCAN_BLOCKS 49                 // ceil(N_NODES/1024); MUST be co-resident (<=256)
#define FUSE_CHUNKS 98                 // 98*8=784>=782 gemm, 98*24=2352>=2344 deg
#define PREP_BLKS  288                 // covers 3*128*(128+64)/256 wtrans threads

typedef short bf16x8 __attribute__((ext_vector_type(8)));
typedef float f32x4  __attribute__((ext_vector_type(4)));

// ---------------- f32 -> bf16 (RNE) ----------------
__device__ __forceinline__ unsigned short f2bf(float f) {
    unsigned u = __float_as_uint(f);
    u = (u + 0x7fffu + ((u >> 16) & 1u)) >> 16;
    return (unsigned short)u;
}
__device__ __forceinline__ unsigned pack_bf2(float lo, float hi) {
    return (unsigned)f2bf(lo) | ((unsigned)f2bf(hi) << 16);
}

// ---------------- W -> fragment-linear bf16 ----------------
// B element (rel, k, n):  frag f = (rel*(ncols/16) + n/16)*4 + k/32
// ushort idx = f*512 + ((k&31)/8)*128 + (n&15)*8 + (k&7)
__device__ __forceinline__ void wtrans_one(
    const float* __restrict__ W, unsigned short* __restrict__ Wtf, int ncols, int i)
{
    int rel = i / (128 * ncols);
    int rem = i - rel * 128 * ncols;
    int k   = rem / ncols;
    int n   = rem - k * ncols;
    int f   = (rel * (ncols / 16) + (n >> 4)) * 4 + (k >> 5);
    int idx = f * 512 + ((k & 31) >> 3) * 128 + (n & 15) * 8 + (k & 7);
    Wtf[idx] = f2bf(W[i]);
}

// prep: weight convert + zero degree counters + zero spin flag (replaces memset)
__global__ __launch_bounds__(256) void prep_kernel(
    const float* __restrict__ W1, unsigned short* __restrict__ Wt1,
    const float* __restrict__ W2, unsigned short* __restrict__ Wt2,
    float* __restrict__ zbuf, int* __restrict__ done)
{
    int i = blockIdx.x * 256 + threadIdx.x;
    if (i == 0) *done = 0;
    for (int q = i; q < 2 * RN; q += PREP_BLKS * 256) zbuf[q] = 0.f;
    if (i < 3 * 128 * 128) {
        wtrans_one(W1, Wt1, 128, i);
    } else {
        int j = i - 3 * 128 * 128;
        if (j < 3 * 128 * 64) wtrans_one(W2, Wt2, 64, j);
    }
}

// ---------------- heavy GEMM body (layer 2): A staged in LDS, W dbuf ----------------
template <bool ABF16, int NCOLS>
__device__ __forceinline__ void gemm_body(
    const void* __restrict__ Av, const unsigned short* __restrict__ Wtf,
    unsigned short* __restrict__ Y, int nrows, int mt,
    unsigned* As, unsigned* Ws0, unsigned* Ws1)
{
    const int tid = threadIdx.x;
    const uint4* Wt4 = (const uint4*)Wtf;

    if constexpr (ABF16) {
        const uint4* Ab = (const uint4*)Av;
        #pragma unroll
        for (int p = 0; p < 4; ++p) {
            int q   = p * 256 + tid;
            int row = q >> 4, w4 = q & 15;
            int gr  = mt + row;
            uint4 v = make_uint4(0u, 0u, 0u, 0u);
            if (gr < nrows) v = Ab[(size_t)gr * 16 + w4];
            As[row * 68 + w4 * 4 + 0] = v.x;
            As[row * 68 + w4 * 4 + 1] = v.y;
            As[row * 68 + w4 * 4 + 2] = v.z;
            As[row * 68 + w4 * 4 + 3] = v.w;
        }
    } else {
        const float* A = (const float*)Av;
        #pragma unroll
        for (int p = 0; p < 16; ++p) {
            int q   = tid + p * 256;
            int row = q >> 6, wc = q & 63;
            int gr  = mt + row;
            float2 v = make_float2(0.f, 0.f);
            if (gr < nrows) v = *reinterpret_cast<const float2*>(&A[(size_t)gr * 128 + wc * 2]);
            As[row * 68 + wc] = pack_bf2(v.x, v.y);
        }
    }

    #pragma unroll
    for (int p = 0; p < 4; ++p) {
        uint4 v = Wt4[tid + p * 256];
        *reinterpret_cast<uint4*>(&Ws0[(tid + p * 256) * 4]) = v;
    }
    __syncthreads();

    const int w  = tid >> 6;
    const int l  = tid & 63;
    const int g  = l >> 4;
    const int lr = l & 15;
    const int ar = w * 16 + lr;

    bf16x8 a[4];
    #pragma unroll
    for (int kb = 0; kb < 4; ++kb)
        a[kb] = *reinterpret_cast<const bf16x8*>(&As[ar * 68 + kb * 16 + g * 4]);

    constexpr int TPR  = NCOLS / 16;
    constexpr int NGRP = 3 * NCOLS / 64;
    const int boff = (g * 16 + lr) * 4;

    unsigned* wc_buf = Ws0;
    unsigned* wn_buf = Ws1;
    #pragma unroll 1
    for (int grp = 0; grp < NGRP; ++grp) {
        uint4 st[4];
        if (grp + 1 < NGRP) {
            #pragma unroll
            for (int p = 0; p < 4; ++p)
                st[p] = Wt4[(grp + 1) * 1024 + tid + p * 256];
        }

        f32x4 acc[4];
        #pragma unroll
        for (int ct4 = 0; ct4 < 4; ++ct4) {
            acc[ct4] = (f32x4){0.f, 0.f, 0.f, 0.f};
            #pragma unroll
            for (int kb = 0; kb < 4; ++kb) {
                bf16x8 b = *reinterpret_cast<const bf16x8*>(
                    &wc_buf[(ct4 * 4 + kb) * 256 + boff]);
                acc[ct4] = __builtin_amdgcn_mfma_f32_16x16x32_bf16(a[kb], b, acc[ct4], 0, 0, 0);
            }
        }

        int gct0 = grp * 4;
        int rel  = gct0 / TPR;
        int cb   = (gct0 % TPR) * 16;
        #pragma unroll
        for (int i = 0; i < 4; ++i) {
            int grow = mt + w * 16 + g * 4 + i;
            if (grow < nrows) {
                size_t rowbase = ((size_t)rel * N_NODES + grow) * NCOLS + cb;
                #pragma unroll
                for (int ct4 = 0; ct4 < 4; ++ct4)
                    Y[rowbase + ct4 * 16 + lr] = f2bf(acc[ct4][i]);
            }
        }

        if (grp + 1 < NGRP) {
            #pragma unroll
            for (int p = 0; p < 4; ++p)
                *reinterpret_cast<uint4*>(&wn_buf[(tid + p * 256) * 4]) = st[p];
        }
        __syncthreads();
        unsigned* t = wc_buf; wc_buf = wn_buf; wn_buf = t;
    }
}

template <bool ABF16, int NCOLS>
__global__ __launch_bounds__(256) void gemm_mfma(
    const void* __restrict__ Av, const unsigned short* __restrict__ Wtf,
    unsigned short* __restrict__ Y, int nrows)
{
    __shared__ unsigned As[64 * 68];
    __shared__ unsigned Ws[2][4096];
    gemm_body<ABF16, NCOLS>(Av, Wtf, Y, nrows, blockIdx.x * 64, As, Ws[0], Ws[1]);
}

// ---------------- LDS-light layer-1 GEMM body (16KB LDS, for fusion) ----------------
__device__ __forceinline__ void gemm1_body_light(
    const float* __restrict__ A, const unsigned short* __restrict__ Wtf,
    unsigned short* __restrict__ Y, int mt, unsigned* Ws)
{
    const int tid = threadIdx.x;
    const uint4* Wt4 = (const uint4*)Wtf;
    const int w  = tid >> 6;
    const int l  = tid & 63;
    const int g  = l >> 4;
    const int lr = l & 15;
    const int arow = mt + w * 16 + lr;
    const bool rowok = arow < N_NODES;

    bf16x8 a[4];
    #pragma unroll
    for (int kb = 0; kb < 4; ++kb) {
        float4 v0 = make_float4(0.f, 0.f, 0.f, 0.f);
        float4 v1 = make_float4(0.f, 0.f, 0.f, 0.f);
        if (rowok) {
            const float* ap = &A[(size_t)arow * 128 + kb * 32 + g * 8];
            v0 = *reinterpret_cast<const float4*>(ap);
            v1 = *reinterpret_cast<const float4*>(ap + 4);
        }
        union { unsigned u[4]; bf16x8 v; } cv;
        cv.u[0] = pack_bf2(v0.x, v0.y);
        cv.u[1] = pack_bf2(v0.z, v0.w);
        cv.u[2] = pack_bf2(v1.x, v1.y);
        cv.u[3] = pack_bf2(v1.z, v1.w);
        a[kb] = cv.v;
    }

    const int boff = (g * 16 + lr) * 4;

    #pragma unroll 1
    for (int grp = 0; grp < 6; ++grp) {
        __syncthreads();
        #pragma unroll
        for (int p = 0; p < 4; ++p) {
            uint4 v = Wt4[grp * 1024 + tid + p * 256];
            *reinterpret_cast<uint4*>(&Ws[(tid + p * 256) * 4]) = v;
        }
        __syncthreads();

        f32x4 acc[4];
        #pragma unroll
        for (int ct4 = 0; ct4 < 4; ++ct4) {
            acc[ct4] = (f32x4){0.f, 0.f, 0.f, 0.f};
            #pragma unroll
            for (int kb = 0; kb < 4; ++kb) {
                bf16x8 b = *reinterpret_cast<const bf16x8*>(
                    &Ws[(ct4 * 4 + kb) * 256 + boff]);
                acc[ct4] = __builtin_amdgcn_mfma_f32_16x16x32_bf16(a[kb], b, acc[ct4], 0, 0, 0);
            }
        }

        int rel = grp >> 1;
        int cb  = (grp & 1) * 64;
        #pragma unroll
        for (int i = 0; i < 4; ++i) {
            int grow = mt + w * 16 + g * 4 + i;
            if (grow < N_NODES) {
                size_t rowbase = ((size_t)rel * N_NODES + grow) * 128 + cb;
                #pragma unroll
                for (int ct4 = 0; ct4 < 4; ++ct4)
                    Y[rowbase + ct4 * 16 + lr] = f2bf(acc[ct4][i]);
            }
        }
    }
}

// ---------------- FUSED: layer-1 GEMM + degree count + rank, chunk-interleaved ----------------
__global__ __launch_bounds__(256) void fused_gemm1_deg(
    const float* __restrict__ x, const unsigned short* __restrict__ Wt1,
    unsigned short* __restrict__ Y,
    const int* __restrict__ src, const int* __restrict__ dst,
    float* __restrict__ odeg, float* __restrict__ ideg,
    unsigned short* __restrict__ rank)
{
    __shared__ unsigned Ws[4096];    // 16KB -> 8 blocks/CU co-tenancy

    const int c = blockIdx.x >> 5;
    const int o = blockIdx.x & 31;

    if (o < 8) {
        int gb = c * 8 + o;
        if (gb >= GEMM1_BLKS) return;
        gemm1_body_light(x, Wt1, Y, gb * 64, Ws);
    } else {
        int db = c * 24 + (o - 8);
        int i  = db * 256 + threadIdx.x;
        if (i < RE) {
            int r = i / N_EDGE;
            int s = src[i], t = dst[i];
            unsafeAtomicAdd(&odeg[r * N_NODES + s], 1.0f);
            float old = unsafeAtomicAdd(&ideg[r * N_NODES + t], 1.0f);
            rank[i] = (unsigned short)(int)old;
        }
    }
}

// ---------------- single-kernel scan: local prefix -> publish -> spin -> finalize ----------------
// 49 blocks (all co-resident on 256 CUs -> spin is deadlock-free).
// Produces: off[t] (combined segment base), roff[r][t] (per-relation sub-segment base),
// converts both count arrays to norms.
__global__ __launch_bounds__(256) void scan_all_kernel(
    float* __restrict__ odeg, float* __restrict__ ideg,
    int* __restrict__ off, int* __restrict__ roff,
    int* __restrict__ bsums, int* __restrict__ done)
{
    __shared__ int tsum[256];
    __shared__ int addsh;
    const int tid  = threadIdx.x;
    const int base = blockIdx.x * 1024 + tid * 4;

    float c0[4], c1[4], c2[4];
    int tot[4], s = 0;
    #pragma unroll
    for (int j = 0; j < 4; ++j) {
        int idx = base + j;
        if (idx < N_NODES) {
            c0[j] = ideg[idx];
            c1[j] = ideg[N_NODES + idx];
            c2[j] = ideg[2 * N_NODES + idx];
            tot[j] = (int)c0[j] + (int)c1[j] + (int)c2[j];
        } else { c0[j] = c1[j] = c2[j] = 0.f; tot[j] = 0; }
        s += tot[j];
    }
    tsum[tid] = s;
    __syncthreads();
    #pragma unroll
    for (int d = 1; d < 256; d <<= 1) {
        int v   = tsum[tid];
        int add = (tid >= d) ? tsum[tid - d] : 0;
        __syncthreads();
        tsum[tid] = v + add;
        __syncthreads();
    }
    int run = tsum[tid] - s;      // exclusive within block

    if (tid == 255) bsums[blockIdx.x] = tsum[255];
    __threadfence();
    if (tid == 0) {
        __hip_atomic_fetch_add(done, 1, __ATOMIC_RELEASE, __HIP_MEMORY_SCOPE_AGENT);
        while (__hip_atomic_load(done, __ATOMIC_ACQUIRE, __HIP_MEMORY_SCOPE_AGENT) < SCAN_BLOCKS)
            __builtin_amdgcn_s_sleep(2);
    }
    __syncthreads();

    if (tid < 64) {
        int v = (tid < blockIdx.x) ? bsums[tid] : 0;   // SCAN_BLOCKS=49 <= 64
        #pragma unroll
        for (int d = 32; d > 0; d >>= 1) v += __shfl_down(v, d, 64);
        if (tid == 0) addsh = v;
    }
    __syncthreads();
    int run2 = run + addsh;

    #pragma unroll
    for (int j = 0; j < 4; ++j) {
        int t = base + j;
        if (t < N_NODES) {
            off[t]                = run2;
            roff[t]               = run2;
            roff[N_NODES + t]     = run2 + (int)c0[j];
            roff[2 * N_NODES + t] = run2 + (int)c0[j] + (int)c1[j];
            ideg[t]               = rsqrtf(fmaxf(c0[j], 1.0f));
            ideg[N_NODES + t]     = rsqrtf(fmaxf(c1[j], 1.0f));
            ideg[2 * N_NODES + t] = rsqrtf(fmaxf(c2[j], 1.0f));
            run2 += tot[j];
        }
    }
    if (blockIdx.x == 0 && tid == 0) off[N_NODES] = RE;

    int q0 = blockIdx.x * 256 + tid;
    for (int q = q0; q < RN; q += SCAN_BLOCKS * 256)
        odeg[q] = rsqrtf(fmaxf(odeg[q], 1.0f));
}

// ---------------- CSR fill, atomic-free, 4B entries: u32 = src<<16 | bf16(weight) ----------------
__global__ __launch_bounds__(256) void fill_kernel(
    const int* __restrict__ src, const int* __restrict__ dst,
    const float* __restrict__ onorm, const float* __restrict__ inorm,
    const int* __restrict__ roff, const unsigned short* __restrict__ rank,
    unsigned* __restrict__ csr)
{
    int i = blockIdx.x * 256 + threadIdx.x;
    if (i >= N_EDGE) return;
    int r   = blockIdx.y;
    int idx = r * N_EDGE + i;
    int s = src[idx], t = dst[idx];
    float wv = onorm[r * N_NODES + s] * inorm[r * N_NODES + t];
    int slot = roff[r * N_NODES + t] + (int)rank[idx];
    csr[slot] = ((unsigned)s << 16) | (unsigned)f2bf(wv);
}

// ---------------- gather aggregation, layer 1 (D=128), 4B CSR, unroll-8 ----------------
// relation derived per entry: r = (e>=r1)+(e>=r2); payload: src=hi16, w=bf16 lo16.
__global__ __launch_bounds__(256) void agg128_kernel(
    const unsigned* __restrict__ Y, const unsigned* __restrict__ csr,
    const int* __restrict__ off, const int* __restrict__ roff,
    const float* __restrict__ b, unsigned* __restrict__ hbf)
{
    int wid  = (blockIdx.x * 256 + threadIdx.x) >> 6;
    int lane = threadIdx.x & 63;
    if (wid >= N_NODES) return;

    int e   = off[wid], end = off[wid + 1];
    int r1  = roff[N_NODES + wid];
    int r2  = roff[2 * N_NODES + wid];
    float a0 = 0.f, a1 = 0.f;

    for (; e + 8 <= end; e += 8) {
        unsigned p[8]; unsigned y[8];
        #pragma unroll
        for (int j = 0; j < 8; ++j) p[j] = csr[e + j];
        #pragma unroll
        for (int j = 0; j < 8; ++j) {
            int rr = (e + j >= r1) + (e + j >= r2);
            y[j] = Y[((size_t)rr * N_NODES + (p[j] >> 16)) * 64 + lane];
        }
        #pragma unroll
        for (int j = 0; j < 8; ++j) {
            float wv = __uint_as_float((p[j] & 0xffffu) << 16);
            a0 = fmaf(wv, __uint_as_float(y[j] << 16), a0);
            a1 = fmaf(wv, __uint_as_float(y[j] & 0xffff0000u), a1);
        }
    }
    if (e + 4 <= end) {
        unsigned p[4]; unsigned y[4];
        #pragma unroll
        for (int j = 0; j < 4; ++j) p[j] = csr[e + j];
        #pragma unroll
        for (int j = 0; j < 4; ++j) {
            int rr = (e + j >= r1) + (e + j >= r2);
            y[j] = Y[((size_t)rr * N_NODES + (p[j] >> 16)) * 64 + lane];
        }
        #pragma unroll
        for (int j = 0; j < 4; ++j) {
            float wv = __uint_as_float((p[j] & 0xffffu) << 16);
            a0 = fmaf(wv, __uint_as_float(y[j] << 16), a0);
            a1 = fmaf(wv, __uint_as_float(y[j] & 0xffff0000u), a1);
        }
        e += 4;
    }
    for (; e < end; ++e) {
        unsigned p = csr[e];
        int rr = (e >= r1) + (e >= r2);
        unsigned y = Y[((size_t)rr * N_NODES + (p >> 16)) * 64 + lane];
        float wv = __uint_as_float((p & 0xffffu) << 16);
        a0 = fmaf(wv, __uint_as_float(y << 16), a0);
        a1 = fmaf(wv, __uint_as_float(y & 0xffff0000u), a1);
    }

    int d = lane * 2;
    float o0 = a0 + b[d]     + b[128 + d]     + b[256 + d];
    float o1 = a1 + b[d + 1] + b[128 + d + 1] + b[256 + d + 1];
    hbf[(size_t)wid * 64 + lane] = pack_bf2(fmaxf(o0, 0.f), fmaxf(o1, 0.f));
}

// ---------------- gather aggregation, layer 2 (D=64), 4B CSR, unroll-8 ----------------
__global__ __launch_bounds__(256) void agg64_kernel(
    const unsigned short* __restrict__ Y, const unsigned* __restrict__ csr,
    const int* __restrict__ off, const int* __restrict__ roff,
    const float* __restrict__ b, float* __restrict__ out)
{
    int wid  = (blockIdx.x * 256 + threadIdx.x) >> 6;
    int lane = threadIdx.x & 63;
    if (wid >= N_NODES) return;

    int e   = off[wid], end = off[wid + 1];
    int r1  = roff[N_NODES + wid];
    int r2  = roff[2 * N_NODES + wid];
    float a = 0.f;

    for (; e + 8 <= end; e += 8) {
        unsigned p[8]; unsigned short y[8];
        #pragma unroll
        for (int j = 0; j < 8; ++j) p[j] = csr[e + j];
        #pragma unroll
        for (int j = 0; j < 8; ++j) {
            int rr = (e + j >= r1) + (e + j >= r2);
            y[j] = Y[((size_t)rr * N_NODES + (p[j] >> 16)) * 64 + lane];
        }
        #pragma unroll
        for (int j = 0; j < 8; ++j)
            a = fmaf(__uint_as_float((p[j] & 0xffffu) << 16),
                     __uint_as_float(((unsigned)y[j]) << 16), a);
    }
    if (e + 4 <= end) {
        unsigned p[4]; unsigned short y[4];
        #pragma unroll
        for (int j = 0; j < 4; ++j) p[j] = csr[e + j];
        #pragma unroll
        for (int j = 0; j < 4; ++j) {
            int rr = (e + j >= r1) + (e + j >= r2);
            y[j] = Y[((size_t)rr * N_NODES + (p[j] >> 16)) * 64 + lane];
        }
        #pragma unroll
        for (int j = 0; j < 4; ++j)
            a = fmaf(__uint_as_float((p[j] & 0xffffu) << 16),
                     __uint_as_float(((unsigned)y[j]) << 16), a);
        e += 4;
    }
    for (; e < end; ++e) {
        unsigned p = csr[e];
        int rr = (e >= r1) + (e >= r2);
        a = fmaf(__uint_as_float((p & 0xffffu) << 16),
                 __uint_as_float(((unsigned)Y[((size_t)rr * N_NODES + (p >> 16)) * 64 + lane]) << 16), a);
    }

    float bs = b[lane] + b[64 + lane] + b[128 + lane];
    out[(size_t)wid * 64 + lane] = a + bs;
}

extern "C" void kernel_launch(void* const* d_in, const int* in_sizes, int n_in,
                              void* d_out, int out_size, void* d_ws, size_t ws_size,
                              hipStream_t stream)
{
    const float* x   = (const float*)d_in[0];   // [N,128]
    const float* W1  = (const float*)d_in[1];   // [3,128,128]
    const float* b1  = (const float*)d_in[2];   // [3,128]
    const float* W2  = (const float*)d_in[3];   // [3,128,64]
    const float* b2  = (const float*)d_in[4];   // [3,64]
    const int*   src = (const int*)d_in[5];     // [3,E]
    const int*   dst = (const int*)d_in[6];     // [3,E]
    float*       out = (float*)d_out;           // [N,64]

    // workspace layout
    char* w = (char*)d_ws;
    float* onorm  = (float*)w;                 w += (size_t)RN * 4;           // counts then norms
    float* inorm  = (float*)w;                 w += (size_t)RN * 4;           // counts then norms
    int*   off    = (int*)w;                   w += (size_t)(N_NODES + 1) * 4;
    int*   roff   = (int*)w;                   w += (size_t)RN * 4;
    int*   bsums  = (int*)w;                   w += 512;
    int*   done   = (int*)w;                   w += 512;
    unsigned short* rank = (unsigned short*)w; w += (size_t)RE * 2;
    w = (char*)(((uintptr_t)w + 255) & ~(uintptr_t)255);
    unsigned* csr = (unsigned*)w;              w += (size_t)RE * 4;
    unsigned* hbf = (unsigned*)w;              w += (size_t)N_NODES * 64 * 4; // bf16 h [N,128]
    unsigned short* Ybf = (unsigned short*)w;  w += (size_t)N_REL * N_NODES * 128 * 2;
    unsigned short* Wt1 = (unsigned short*)w;  w += (size_t)N_REL * 128 * 128 * 2;
    unsigned short* Wt2 = (unsigned short*)w;  // 3*64*128*2

    // 0) prep: weight convert + zero counters + zero spin flag (one dispatch)
    prep_kernel<<<PREP_BLKS, 256, 0, stream>>>(W1, Wt1, W2, Wt2, onorm, done);

    // 1) FUSED interleaved: gemm1 (x@W1 -> Ybf) + degrees + ranks
    fused_gemm1_deg<<<FUSE_CHUNKS * 32, 256, 0, stream>>>(
        x, Wt1, Ybf, src, dst, onorm, inorm, rank);

    // 2) single-kernel scan: off/roff bases + counts->norms (spin-synced, 49 blocks)
    scan_all_kernel<<<SCAN_BLOCKS, 256, 0, stream>>>(onorm, inorm, off, roff, bsums, done);

    // 3) CSR fill (atomic-free, 4B entries)
    fill_kernel<<<dim3((N_EDGE + 255) / 256, N_REL), 256, 0, stream>>>(
        src, dst, onorm, inorm, roff, rank, csr);

    // 4) layer 1 aggregate + bias + ReLU -> hbf (bf16)
    agg128_kernel<<<(N_NODES + 3) / 4, 256, 0, stream>>>(
        (const unsigned*)Ybf, csr, off, roff, b1, hbf);

    // 5) layer 2: Y_r = hbf @ W2_r (bf16, MFMA), gather-aggregate into out
    gemm_mfma<true, 64><<<GEMM1_BLKS, 256, 0, stream>>>(hbf, Wt2, Ybf, N_NODES);
    agg64_kernel<<<(N_NODES + 3) / 4, 256, 0, stream>>>(Ybf, csr, off, roff, b2, out);
}